// Round 3
// baseline (660.106 us; speedup 1.0000x reference)
//
#include <hip/hip_runtime.h>
#include <hip/hip_bf16.h>

typedef unsigned short u16;
typedef unsigned int   u32;

#define NN 50000
#define EE 1600000
#define DD 128
#define DYY 64

__device__ __forceinline__ float bf2f(u32 u){ return __uint_as_float(u << 16); }
__device__ __forceinline__ u16 f2bf(float f){
  u32 u = __float_as_uint(f);
  u += 0x7FFFu + ((u >> 16) & 1u);   // round-to-nearest-even
  return (u16)(u >> 16);
}
// adaptive scalar load: isbf ? bf16[i] : fp32[i]
__device__ __forceinline__ float ldv(const void* p, int i, int isbf){
  return isbf ? bf2f((u32)((const u16*)p)[i]) : ((const float*)p)[i];
}

__device__ __forceinline__ float wave_sum(float v){
  #pragma unroll
  for (int s = 32; s; s >>= 1) v += __shfl_xor(v, s, 64);
  return v;
}
__device__ __forceinline__ float wave_max(float v){
  #pragma unroll
  for (int s = 32; s; s >>= 1) v = fmaxf(v, __shfl_xor(v, s, 64));
  return v;
}

// dtype probe on W1: low-u16 bits14..7 are a bf16 exponent (concentrated) if inputs
// are bf16-packed, or uniform fp32 mantissa bits if fp32. Writes 1=bf16, 0=fp32.
__global__ void k_detect(const u32* __restrict__ w1, int* __restrict__ flagp){
  __shared__ int cnt_s;
  if (threadIdx.x == 0) cnt_s = 0;
  __syncthreads();
  int c = 0;
  for (int i = threadIdx.x; i < 2048; i += 256){
    u32 b = (w1[i] >> 7) & 0xFFu;
    if (b >= 100u && b <= 130u) c++;
  }
  atomicAdd(&cnt_s, c);
  __syncthreads();
  if (threadIdx.x == 0) *flagp = (cnt_s > 1600) ? 1 : 0;
}

__global__ void k_zero(int* __restrict__ p, int n){
  int i = blockIdx.x * blockDim.x + threadIdx.x;
  if (i < n) p[i] = 0;
}

__global__ void k_count(const int* __restrict__ dst, int* __restrict__ cnt){
  int e = blockIdx.x * blockDim.x + threadIdx.x;
  if (e < EE) atomicAdd(&cnt[dst[e]], 1);
}

// per-256-chunk exclusive scan; chunk totals -> bsums
__global__ void k_scan1(const int* __restrict__ cnt, int* __restrict__ offs, int* __restrict__ bsums){
  __shared__ int sd[256];
  int tid = threadIdx.x;
  int i = blockIdx.x * 256 + tid;
  int v = (i < NN) ? cnt[i] : 0;
  sd[tid] = v;
  __syncthreads();
  for (int o = 1; o < 256; o <<= 1){
    int t = (tid >= o) ? sd[tid - o] : 0;
    __syncthreads();
    sd[tid] += t;
    __syncthreads();
  }
  if (i < NN) offs[i] = sd[tid] - v;
  if (tid == 255) bsums[blockIdx.x] = sd[255];
}

__global__ void k_scan2(int* __restrict__ bsums, int nch){
  __shared__ int sd[256];
  int tid = threadIdx.x;
  int v = (tid < nch) ? bsums[tid] : 0;
  sd[tid] = v;
  __syncthreads();
  for (int o = 1; o < 256; o <<= 1){
    int t = (tid >= o) ? sd[tid - o] : 0;
    __syncthreads();
    sd[tid] += t;
    __syncthreads();
  }
  bsums[tid] = sd[tid] - v;
}

__global__ void k_scan3(int* __restrict__ offs, const int* __restrict__ bsums, int* __restrict__ cursor){
  int i = blockIdx.x * blockDim.x + threadIdx.x;
  if (i < NN){
    int o = offs[i] + bsums[i >> 8];
    offs[i] = o;
    cursor[i] = o;
  }
}

// scatter src ids (u16: N < 65536) into dst-sorted CSR slots; topology-only, built once
__global__ void k_fill(const int* __restrict__ src, const int* __restrict__ dst,
                       int* __restrict__ cursor, u16* __restrict__ srcs){
  int e = blockIdx.x * blockDim.x + threadIdx.x;
  if (e >= EE) return;
  int d = dst[e];
  int pos = atomicAdd(&cursor[d], 1);
  srcs[pos] = (u16)src[e];
}

// H[row][col] = sum_k X[row][k]*W[k][col]; X/W adaptive dtype, H canonical bf16
__global__ __launch_bounds__(256) void k_gemm(const void* __restrict__ X,
                                              const void* __restrict__ W,
                                              u16* __restrict__ Hout,
                                              const int* __restrict__ flagp, int xext){
  __shared__ u16 Ws[DD * DD];   // 32 KB
  __shared__ float Xs[16 * DD]; // 8 KB
  int isbf = *flagp;
  int tid = threadIdx.x;
  if (isbf){
    const u32* Wv = (const u32*)W;
    u32* Wsv = (u32*)Ws;
    for (int k = tid; k < DD * DD / 2; k += 256) Wsv[k] = Wv[k];
  } else {
    const float* Wf = (const float*)W;
    for (int k = tid; k < DD * DD; k += 256) Ws[k] = f2bf(Wf[k]);
  }
  int row0 = blockIdx.x * 16;
  int xbf = xext ? isbf : 1;   // internal buffers are always bf16
  if (xbf){
    const u32* Xv = (const u32*)((const u16*)X + (size_t)row0 * DD);
    for (int idx = tid; idx < 16 * DD / 2; idx += 256){
      u32 u = Xv[idx];
      Xs[2 * idx]     = bf2f(u & 0xffffu);
      Xs[2 * idx + 1] = bf2f(u >> 16);
    }
  } else {
    const float* Xf = (const float*)X + (size_t)row0 * DD;
    for (int idx = tid; idx < 16 * DD; idx += 256) Xs[idx] = Xf[idx];
  }
  __syncthreads();
  int col = tid & 127;
  int rb  = (tid >> 7) * 8;
  float acc[8] = {0,0,0,0,0,0,0,0};
  for (int k = 0; k < DD; ++k){
    float w = bf2f((u32)Ws[k * DD + col]);
    #pragma unroll
    for (int rr = 0; rr < 8; ++rr) acc[rr] += Xs[(rb + rr) * DD + k] * w;
  }
  #pragma unroll
  for (int rr = 0; rr < 8; ++rr)
    Hout[(size_t)(row0 + rb + rr) * DD + col] = f2bf(acc[rr]);
}

// per-node logit halves: Sv = h.att_src, Dv = h.att_dst (one wave per row, bf16 H)
__global__ __launch_bounds__(256) void k_sd(const u16* __restrict__ H,
                                            const void* __restrict__ as,
                                            const void* __restrict__ ad,
                                            float* __restrict__ Sv, float* __restrict__ Dv,
                                            const int* __restrict__ flagp){
  int isbf = *flagp;
  int gid = blockIdx.x * blockDim.x + threadIdx.x;
  int wid = gid >> 6, lane = gid & 63;
  if (wid >= NN) return;
  u32 hv = ((const u32*)H)[(size_t)wid * 64 + lane];
  float h0 = bf2f(hv & 0xffffu), h1 = bf2f(hv >> 16);
  float a0 = ldv(as, 2 * lane, isbf), a1 = ldv(as, 2 * lane + 1, isbf);
  float d0 = ldv(ad, 2 * lane, isbf), d1 = ldv(ad, 2 * lane + 1, isbf);
  float s = wave_sum(h0 * a0 + h1 * a1);
  float d = wave_sum(h0 * d0 + h1 * d1);
  if (lane == 0){ Sv[wid] = s; Dv[wid] = d; }
}

// one wave per destination: softmax over incoming edges (+ analytic self-loop), weighted gather
__global__ __launch_bounds__(256) void k_agg(const u16* __restrict__ H,
                                             const float* __restrict__ Sv, const float* __restrict__ Dv,
                                             const int* __restrict__ offs, const int* __restrict__ cnt,
                                             const u16* __restrict__ srcs,
                                             const void* __restrict__ bias,
                                             u16* __restrict__ Xout, int do_relu,
                                             const int* __restrict__ flagp){
  int isbf = *flagp;
  int gid = blockIdx.x * blockDim.x + threadIdx.x;
  int wid = gid >> 6, lane = gid & 63;
  if (wid >= NN) return;
  int off = offs[wid], c = cnt[wid];
  float dvw = Dv[wid];
  float eself = fmaxf(Sv[wid] + dvw, 0.f);
  // pass 1: max source-logit over incoming edges
  float mS = -1e30f;
  for (int base = 0; base < c; base += 64){
    int j = base + lane;
    float s = (j < c) ? Sv[(int)srcs[off + j]] : -1e30f;
    mS = fmaxf(mS, s);
  }
  mS = wave_max(mS);
  // relu monotone: max_j relu(s_j + d) = relu(max_j s_j + d); self term >= 0 dominates empties
  float m = fmaxf(eself, fmaxf(mS + dvw, 0.f));
  const u32* H2 = (const u32*)H;
  u32 hv = H2[(size_t)wid * 64 + lane];
  float wself = __expf(eself - m);
  float ax = wself * bf2f(hv & 0xffffu);
  float ay = wself * bf2f(hv >> 16);
  float dl = 0.f;
  // pass 2: exp weights + weighted bf16 row gather
  for (int base = 0; base < c; base += 64){
    int j = base + lane;
    bool valid = j < c;
    int sidx = valid ? (int)srcs[off + j] : 0;
    float e   = valid ? fmaxf(Sv[sidx] + dvw, 0.f) : 0.f;
    float wgt = valid ? __expf(e - m) : 0.f;
    dl += wgt;
    int lim = min(64, c - base);
    for (int t = 0; t < lim; ++t){
      float wt = __shfl(wgt, t, 64);
      int st   = __shfl(sidx, t, 64);
      u32 rv = H2[(size_t)st * 64 + lane];
      ax += wt * bf2f(rv & 0xffffu);
      ay += wt * bf2f(rv >> 16);
    }
  }
  float denom = wave_sum(dl) + wself;  // >= wself > 0
  float inv = 1.f / denom;
  float b0 = ldv(bias, 2 * lane, isbf), b1 = ldv(bias, 2 * lane + 1, isbf);
  float o0 = ax * inv + b0, o1 = ay * inv + b1;
  if (do_relu){ o0 = fmaxf(o0, 0.f); o1 = fmaxf(o1, 0.f); }
  u32 pk = ((u32)f2bf(o1) << 16) | (u32)f2bf(o0);
  ((u32*)Xout)[(size_t)wid * 64 + lane] = pk;
}

// out[row][col] = sum_k X[row][k]*Wout[k][col] + b[col]; store dtype matches input flavor
__global__ __launch_bounds__(256) void k_out(const u16* __restrict__ X,
                                             const void* __restrict__ W,
                                             const void* __restrict__ b,
                                             void* __restrict__ out,
                                             const int* __restrict__ flagp){
  __shared__ float Ws[DD * DYY];  // 32 KB
  __shared__ float Xs[16 * DD];   // 8 KB
  int isbf = *flagp;
  int tid = threadIdx.x;
  if (isbf){
    const u32* Wv = (const u32*)W;
    for (int k = tid; k < DD * DYY / 2; k += 256){
      u32 u = Wv[k];
      Ws[2 * k]     = bf2f(u & 0xffffu);
      Ws[2 * k + 1] = bf2f(u >> 16);
    }
  } else {
    const float* Wf = (const float*)W;
    for (int k = tid; k < DD * DYY; k += 256) Ws[k] = Wf[k];
  }
  int row0 = blockIdx.x * 16;
  const u32* Xv = (const u32*)(X + (size_t)row0 * DD);
  for (int idx = tid; idx < 16 * DD / 2; idx += 256){
    u32 u = Xv[idx];
    Xs[2 * idx]     = bf2f(u & 0xffffu);
    Xs[2 * idx + 1] = bf2f(u >> 16);
  }
  __syncthreads();
  int col = tid & 63;
  int rb  = (tid >> 6) * 4;
  float acc[4] = {0,0,0,0};
  for (int k = 0; k < DD; ++k){
    float w = Ws[k * DYY + col];
    #pragma unroll
    for (int rr = 0; rr < 4; ++rr) acc[rr] += Xs[(rb + rr) * DD + k] * w;
  }
  float bo = ldv(b, col, isbf);
  #pragma unroll
  for (int rr = 0; rr < 4; ++rr){
    float v = acc[rr] + bo;
    size_t oi = (size_t)(row0 + rb + rr) * DYY + col;
    if (isbf) ((u16*)out)[oi] = f2bf(v);
    else      ((float*)out)[oi] = v;
  }
}

extern "C" void kernel_launch(void* const* d_in, const int* in_sizes, int n_in,
                              void* d_out, int out_size, void* d_ws, size_t ws_size,
                              hipStream_t stream) {
  const void* node_x = d_in[0];
  const int* ei   = (const int*)d_in[1];
  const int* srcp = ei;
  const int* dstp = ei + EE;
  const void* W1  = d_in[2];
  const void* as1 = d_in[3];
  const void* ad1 = d_in[4];
  const void* b1  = d_in[5];
  const void* W2  = d_in[6];
  const void* as2 = d_in[7];
  const void* ad2 = d_in[8];
  const void* b2  = d_in[9];
  const void* Wo  = d_in[10];
  const void* bo  = d_in[11];

  // workspace carve: ~30 MB
  char* w = (char*)d_ws;
  u16*   Hbf  = (u16*)w;   w += (size_t)NN * DD * 2;  // 12.8 MB  h (bf16)
  u16*   Abf  = (u16*)w;   w += (size_t)NN * DD * 2;  // 12.8 MB  x1/x2 (bf16)
  float* Sv   = (float*)w; w += (size_t)NN * 4;
  float* Dv   = (float*)w; w += (size_t)NN * 4;
  int*   cnt  = (int*)w;   w += (size_t)NN * 4;
  int*   offs = (int*)w;   w += (size_t)NN * 4;
  int*   curs = (int*)w;   w += (size_t)NN * 4;
  int*   flagp= (int*)w;   w += 16;
  int*   bsum = (int*)w;   w += 1024;
  u16*   srcs = (u16*)w;   w += (size_t)EE * 2;       // 3.2 MB

  const int TB = 256;
  const int gN   = (NN + TB - 1) / TB;   // 196
  const int gE   = EE / TB;              // 6250
  const int gWav = (NN * 64) / TB;       // 12500 (one wave per node)
  const int gRow = NN / 16;              // 3125

  // dtype probe + CSR build (topology-only, shared by both layers)
  k_detect<<<1,  TB, 0, stream>>>((const u32*)W1, flagp);
  k_zero <<<gN, TB, 0, stream>>>(cnt, NN);
  k_count<<<gE, TB, 0, stream>>>(dstp, cnt);
  k_scan1<<<gN, TB, 0, stream>>>(cnt, offs, bsum);
  k_scan2<<<1,  TB, 0, stream>>>(bsum, gN);
  k_scan3<<<gN, TB, 0, stream>>>(offs, bsum, curs);
  k_fill <<<gE, TB, 0, stream>>>(srcp, dstp, curs, srcs);

  // ---- layer 1 ----
  k_gemm<<<gRow, TB, 0, stream>>>(node_x, W1, Hbf, flagp, 1);
  k_sd  <<<gWav, TB, 0, stream>>>(Hbf, as1, ad1, Sv, Dv, flagp);
  k_agg <<<gWav, TB, 0, stream>>>(Hbf, Sv, Dv, offs, cnt, srcs, b1, Abf, 1, flagp);

  // ---- layer 2 ----
  k_gemm<<<gRow, TB, 0, stream>>>(Abf, W2, Hbf, flagp, 0);
  k_sd  <<<gWav, TB, 0, stream>>>(Hbf, as2, ad2, Sv, Dv, flagp);
  k_agg <<<gWav, TB, 0, stream>>>(Hbf, Sv, Dv, offs, cnt, srcs, b2, Abf, 0, flagp);

  // ---- output projection ----
  k_out <<<gRow, TB, 0, stream>>>(Abf, Wo, bo, d_out, flagp);
}

// Round 4
// 455.929 us; speedup vs baseline: 1.4478x; 1.4478x over previous
//
#include <hip/hip_runtime.h>
#include <hip/hip_bf16.h>

typedef unsigned short u16;
typedef unsigned int   u32;

#define NN 50000
#define EE 1600000
#define DD 128
#define DYY 64
#define NB 196      // dst buckets: dst>>8, 49999>>8 = 195
#define EPB 8192    // edges per bucketing block
#define GB 196      // ceil(EE/EPB)

__device__ __forceinline__ float bf2f(u32 u){ return __uint_as_float(u << 16); }
__device__ __forceinline__ u16 f2bf(float f){
  u32 u = __float_as_uint(f);
  u += 0x7FFFu + ((u >> 16) & 1u);   // round-to-nearest-even
  return (u16)(u >> 16);
}
// adaptive scalar load: isbf ? bf16[i] : fp32[i]
__device__ __forceinline__ float ldv(const void* p, int i, int isbf){
  return isbf ? bf2f((u32)((const u16*)p)[i]) : ((const float*)p)[i];
}

__device__ __forceinline__ float wave_sum(float v){
  #pragma unroll
  for (int s = 32; s; s >>= 1) v += __shfl_xor(v, s, 64);
  return v;
}
__device__ __forceinline__ float wave_max(float v){
  #pragma unroll
  for (int s = 32; s; s >>= 1) v = fmaxf(v, __shfl_xor(v, s, 64));
  return v;
}

// dtype probe on W1 (proved fp32 in round 3, kept for robustness)
__global__ void k_detect(const u32* __restrict__ w1, int* __restrict__ flagp){
  __shared__ int cnt_s;
  if (threadIdx.x == 0) cnt_s = 0;
  __syncthreads();
  int c = 0;
  for (int i = threadIdx.x; i < 2048; i += 256){
    u32 b = (w1[i] >> 7) & 0xFFu;
    if (b >= 100u && b <= 130u) c++;
  }
  atomicAdd(&cnt_s, c);
  __syncthreads();
  if (threadIdx.x == 0) *flagp = (cnt_s > 1600) ? 1 : 0;
}

__global__ void k_zero(int* __restrict__ p, int n){
  int i = blockIdx.x * blockDim.x + threadIdx.x;
  if (i < n) p[i] = 0;
}

// ---- CSR build: locality-aware counting sort by dst ----
// phase 1: bucket totals via LDS histograms (38k global atomics instead of 1.6M)
__global__ __launch_bounds__(256) void kb_count(const int* __restrict__ dst, int* __restrict__ btot){
  __shared__ int hist[256];
  int tid = threadIdx.x;
  hist[tid] = 0;
  __syncthreads();
  int e0 = blockIdx.x * EPB, e1 = min(e0 + EPB, EE);
  for (int e = e0 + tid; e < e1; e += 256) atomicAdd(&hist[dst[e] >> 8], 1);
  __syncthreads();
  if (tid < NB && hist[tid]) atomicAdd(&btot[tid], hist[tid]);
}

// phase 2: exclusive scan of bucket totals (one block)
__global__ void kb_bscan(const int* __restrict__ btot, int* __restrict__ bbase, int* __restrict__ bcur){
  __shared__ int sd[256];
  int tid = threadIdx.x;
  int v = (tid < NB) ? btot[tid] : 0;
  sd[tid] = v;
  __syncthreads();
  for (int o = 1; o < 256; o <<= 1){
    int t = (tid >= o) ? sd[tid - o] : 0;
    __syncthreads();
    sd[tid] += t;
    __syncthreads();
  }
  if (tid < NB){ bbase[tid] = sd[tid] - v; bcur[tid] = sd[tid] - v; }
}

// phase 3: scatter (src | dlow<<16) into bucket-contiguous buf; block reserves
// contiguous per-bucket ranges -> writes are ~170B sequential runs, not random lines
__global__ __launch_bounds__(256) void kb_scatter(const int* __restrict__ src, const int* __restrict__ dst,
                                                  int* __restrict__ bcur, u32* __restrict__ buf){
  __shared__ int hist[256];
  __shared__ int lcur[256];
  int tid = threadIdx.x;
  hist[tid] = 0;
  __syncthreads();
  int e0 = blockIdx.x * EPB, e1 = min(e0 + EPB, EE);
  for (int e = e0 + tid; e < e1; e += 256) atomicAdd(&hist[dst[e] >> 8], 1);
  __syncthreads();
  if (tid < NB && hist[tid]) lcur[tid] = atomicAdd(&bcur[tid], hist[tid]);
  __syncthreads();
  for (int e = e0 + tid; e < e1; e += 256){
    int d = dst[e];
    int pos = atomicAdd(&lcur[d >> 8], 1);
    buf[pos] = (u32)src[e] | ((u32)(d & 255) << 16);
  }
}

// phase 4: per-bucket finalize — per-dst counts + offsets via LDS scan, then scatter
// src ids into the bucket's 16KB CSR region (L2-resident). Produces offs/cnt/srcs.
__global__ __launch_bounds__(256) void kb_finalize(const u32* __restrict__ buf,
                                                   const int* __restrict__ btot, const int* __restrict__ bbase,
                                                   int* __restrict__ offs, int* __restrict__ cnt,
                                                   u16* __restrict__ srcs){
  __shared__ int dh[256];
  __shared__ int sd[256];
  __shared__ int dcur[256];
  int tid = threadIdx.x, b = blockIdx.x;
  int n = btot[b], base = bbase[b];
  dh[tid] = 0;
  __syncthreads();
  for (int i = tid; i < n; i += 256) atomicAdd(&dh[(buf[base + i] >> 16) & 255], 1);
  __syncthreads();
  int v = dh[tid];
  sd[tid] = v;
  __syncthreads();
  for (int o = 1; o < 256; o <<= 1){
    int t = (tid >= o) ? sd[tid - o] : 0;
    __syncthreads();
    sd[tid] += t;
    __syncthreads();
  }
  int excl = sd[tid] - v;
  dcur[tid] = base + excl;
  int d = (b << 8) + tid;
  if (d < NN){ offs[d] = base + excl; cnt[d] = v; }
  __syncthreads();
  for (int i = tid; i < n; i += 256){
    u32 u = buf[base + i];
    int pos = atomicAdd(&dcur[(u >> 16) & 255], 1);
    srcs[pos] = (u16)(u & 0xffffu);
  }
}

// H[row][col] = sum_k X[row][k]*W[k][col]; X/W adaptive dtype, H canonical bf16
__global__ __launch_bounds__(256) void k_gemm(const void* __restrict__ X,
                                              const void* __restrict__ W,
                                              u16* __restrict__ Hout,
                                              const int* __restrict__ flagp, int xext){
  __shared__ u16 Ws[DD * DD];   // 32 KB
  __shared__ float Xs[16 * DD]; // 8 KB
  int isbf = *flagp;
  int tid = threadIdx.x;
  if (isbf){
    const u32* Wv = (const u32*)W;
    u32* Wsv = (u32*)Ws;
    for (int k = tid; k < DD * DD / 2; k += 256) Wsv[k] = Wv[k];
  } else {
    const float* Wf = (const float*)W;
    for (int k = tid; k < DD * DD; k += 256) Ws[k] = f2bf(Wf[k]);
  }
  int row0 = blockIdx.x * 16;
  int xbf = xext ? isbf : 1;   // internal buffers are always bf16
  if (xbf){
    const u32* Xv = (const u32*)((const u16*)X + (size_t)row0 * DD);
    for (int idx = tid; idx < 16 * DD / 2; idx += 256){
      u32 u = Xv[idx];
      Xs[2 * idx]     = bf2f(u & 0xffffu);
      Xs[2 * idx + 1] = bf2f(u >> 16);
    }
  } else {
    const float* Xf = (const float*)X + (size_t)row0 * DD;
    for (int idx = tid; idx < 16 * DD; idx += 256) Xs[idx] = Xf[idx];
  }
  __syncthreads();
  int col = tid & 127;
  int rb  = (tid >> 7) * 8;
  float acc[8] = {0,0,0,0,0,0,0,0};
  for (int k = 0; k < DD; ++k){
    float w = bf2f((u32)Ws[k * DD + col]);
    #pragma unroll
    for (int rr = 0; rr < 8; ++rr) acc[rr] += Xs[(rb + rr) * DD + k] * w;
  }
  #pragma unroll
  for (int rr = 0; rr < 8; ++rr)
    Hout[(size_t)(row0 + rb + rr) * DD + col] = f2bf(acc[rr]);
}

// per-node logit halves: Sv = h.att_src, Dv = h.att_dst (one wave per row, bf16 H)
__global__ __launch_bounds__(256) void k_sd(const u16* __restrict__ H,
                                            const void* __restrict__ as,
                                            const void* __restrict__ ad,
                                            float* __restrict__ Sv, float* __restrict__ Dv,
                                            const int* __restrict__ flagp){
  int isbf = *flagp;
  int gid = blockIdx.x * blockDim.x + threadIdx.x;
  int wid = gid >> 6, lane = gid & 63;
  if (wid >= NN) return;
  u32 hv = ((const u32*)H)[(size_t)wid * 64 + lane];
  float h0 = bf2f(hv & 0xffffu), h1 = bf2f(hv >> 16);
  float a0 = ldv(as, 2 * lane, isbf), a1 = ldv(as, 2 * lane + 1, isbf);
  float d0 = ldv(ad, 2 * lane, isbf), d1 = ldv(ad, 2 * lane + 1, isbf);
  float s = wave_sum(h0 * a0 + h1 * a1);
  float d = wave_sum(h0 * d0 + h1 * d1);
  if (lane == 0){ Sv[wid] = s; Dv[wid] = d; }
}

// one wave per destination: softmax over incoming edges (+ analytic self-loop).
// 4 lane-groups of 16 each gather one row/iter via dwordx4 (8 bf16/lane) — no
// serialized shfl-broadcast; cross-group reduce at the end.
__global__ __launch_bounds__(256) void k_agg(const u16* __restrict__ H,
                                             const float* __restrict__ Sv, const float* __restrict__ Dv,
                                             const int* __restrict__ offs, const int* __restrict__ cnt,
                                             const u16* __restrict__ srcs,
                                             const void* __restrict__ bias,
                                             u16* __restrict__ Xout, int do_relu,
                                             const int* __restrict__ flagp){
  int isbf = *flagp;
  int gid = blockIdx.x * blockDim.x + threadIdx.x;
  int wid = gid >> 6, lane = gid & 63;
  if (wid >= NN) return;
  int off = offs[wid], c = cnt[wid];
  float dvw = Dv[wid];
  float eself = fmaxf(Sv[wid] + dvw, 0.f);
  // pass 1: max source-logit over incoming edges (lane-per-edge)
  float mS = -1e30f;
  for (int base = 0; base < c; base += 64){
    int j = base + lane;
    float s = (j < c) ? Sv[(int)srcs[off + j]] : -1e30f;
    mS = fmaxf(mS, s);
  }
  mS = wave_max(mS);
  // relu monotone: max_j relu(s_j + d) = relu(max_j s_j + d); self term >= 0 covers c==0
  float m = fmaxf(eself, fmaxf(mS + dvw, 0.f));
  int grp = lane >> 4, cg = lane & 15;
  const u32* H32 = (const u32*)H;
  float wself = __expf(eself - m);
  float acc[8] = {0,0,0,0,0,0,0,0};
  if (grp == 0){
    uint4 r = *(const uint4*)(H32 + (size_t)wid * 64 + cg * 4);
    acc[0] = wself * bf2f(r.x & 0xffffu); acc[1] = wself * bf2f(r.x >> 16);
    acc[2] = wself * bf2f(r.y & 0xffffu); acc[3] = wself * bf2f(r.y >> 16);
    acc[4] = wself * bf2f(r.z & 0xffffu); acc[5] = wself * bf2f(r.z >> 16);
    acc[6] = wself * bf2f(r.w & 0xffffu); acc[7] = wself * bf2f(r.w >> 16);
  }
  float dl = 0.f;
  for (int base = 0; base < c; base += 4){
    int j = base + grp;
    bool valid = j < c;
    int sidx = valid ? (int)srcs[off + j] : 0;
    float e = fmaxf(Sv[sidx] + dvw, 0.f);
    float wgt = valid ? __expf(e - m) : 0.f;
    if (cg == 0) dl += wgt;
    uint4 r = *(const uint4*)(H32 + (size_t)sidx * 64 + cg * 4);
    acc[0] += wgt * bf2f(r.x & 0xffffu); acc[1] += wgt * bf2f(r.x >> 16);
    acc[2] += wgt * bf2f(r.y & 0xffffu); acc[3] += wgt * bf2f(r.y >> 16);
    acc[4] += wgt * bf2f(r.z & 0xffffu); acc[5] += wgt * bf2f(r.z >> 16);
    acc[6] += wgt * bf2f(r.w & 0xffffu); acc[7] += wgt * bf2f(r.w >> 16);
  }
  #pragma unroll
  for (int i = 0; i < 8; ++i){
    acc[i] += __shfl_xor(acc[i], 16, 64);
    acc[i] += __shfl_xor(acc[i], 32, 64);
  }
  float denom = wave_sum(dl) + wself;  // >= wself > 0
  float inv = 1.f / denom;
  if (grp == 0){
    uint4 pk;
    u32* pkp = (u32*)&pk;
    #pragma unroll
    for (int q = 0; q < 4; ++q){
      float o0 = acc[2 * q]     * inv + ldv(bias, cg * 8 + 2 * q,     isbf);
      float o1 = acc[2 * q + 1] * inv + ldv(bias, cg * 8 + 2 * q + 1, isbf);
      if (do_relu){ o0 = fmaxf(o0, 0.f); o1 = fmaxf(o1, 0.f); }
      pkp[q] = ((u32)f2bf(o1) << 16) | (u32)f2bf(o0);
    }
    *(uint4*)((u32*)Xout + (size_t)wid * 64 + cg * 4) = pk;
  }
}

// out[row][col] = sum_k X[row][k]*Wout[k][col] + b[col]; store dtype matches input flavor
__global__ __launch_bounds__(256) void k_out(const u16* __restrict__ X,
                                             const void* __restrict__ W,
                                             const void* __restrict__ b,
                                             void* __restrict__ out,
                                             const int* __restrict__ flagp){
  __shared__ float Ws[DD * DYY];  // 32 KB
  __shared__ float Xs[16 * DD];   // 8 KB
  int isbf = *flagp;
  int tid = threadIdx.x;
  if (isbf){
    const u32* Wv = (const u32*)W;
    for (int k = tid; k < DD * DYY / 2; k += 256){
      u32 u = Wv[k];
      Ws[2 * k]     = bf2f(u & 0xffffu);
      Ws[2 * k + 1] = bf2f(u >> 16);
    }
  } else {
    const float* Wf = (const float*)W;
    for (int k = tid; k < DD * DYY; k += 256) Ws[k] = Wf[k];
  }
  int row0 = blockIdx.x * 16;
  const u32* Xv = (const u32*)(X + (size_t)row0 * DD);
  for (int idx = tid; idx < 16 * DD / 2; idx += 256){
    u32 u = Xv[idx];
    Xs[2 * idx]     = bf2f(u & 0xffffu);
    Xs[2 * idx + 1] = bf2f(u >> 16);
  }
  __syncthreads();
  int col = tid & 63;
  int rb  = (tid >> 6) * 4;
  float acc[4] = {0,0,0,0};
  for (int k = 0; k < DD; ++k){
    float w = Ws[k * DYY + col];
    #pragma unroll
    for (int rr = 0; rr < 4; ++rr) acc[rr] += Xs[(rb + rr) * DD + k] * w;
  }
  float bo = ldv(b, col, isbf);
  #pragma unroll
  for (int rr = 0; rr < 4; ++rr){
    float v = acc[rr] + bo;
    size_t oi = (size_t)(row0 + rb + rr) * DYY + col;
    if (isbf) ((u16*)out)[oi] = f2bf(v);
    else      ((float*)out)[oi] = v;
  }
}

extern "C" void kernel_launch(void* const* d_in, const int* in_sizes, int n_in,
                              void* d_out, int out_size, void* d_ws, size_t ws_size,
                              hipStream_t stream) {
  const void* node_x = d_in[0];
  const int* ei   = (const int*)d_in[1];
  const int* srcp = ei;
  const int* dstp = ei + EE;
  const void* W1  = d_in[2];
  const void* as1 = d_in[3];
  const void* ad1 = d_in[4];
  const void* b1  = d_in[5];
  const void* W2  = d_in[6];
  const void* as2 = d_in[7];
  const void* ad2 = d_in[8];
  const void* b2  = d_in[9];
  const void* Wo  = d_in[10];
  const void* bo  = d_in[11];

  // workspace carve: ~30 MB. buf aliases Abf (dead until first k_agg write).
  char* w = (char*)d_ws;
  u16*   Hbf  = (u16*)w;   w += (size_t)NN * DD * 2;  // 12.8 MB
  u16*   Abf  = (u16*)w;   w += (size_t)NN * DD * 2;  // 12.8 MB (aliased by buf during CSR build)
  u32*   buf  = (u32*)Abf;                             // 6.4 MB, fits in Abf
  float* Sv   = (float*)w; w += (size_t)NN * 4;
  float* Dv   = (float*)w; w += (size_t)NN * 4;
  int*   cnt  = (int*)w;   w += (size_t)NN * 4;
  int*   offs = (int*)w;   w += (size_t)NN * 4;
  int*   flagp= (int*)w;   w += 16;
  int*   btot = (int*)w;   w += 1024;
  int*   bbase= (int*)w;   w += 1024;
  int*   bcur = (int*)w;   w += 1024;
  u16*   srcs = (u16*)w;   w += (size_t)EE * 2;       // 3.2 MB

  const int TB = 256;
  const int gWav = (NN * 64) / TB;       // 12500 (one wave per node)
  const int gRow = NN / 16;              // 3125

  // dtype probe + CSR build (topology-only, shared by both layers)
  k_detect   <<<1,  TB, 0, stream>>>((const u32*)W1, flagp);
  k_zero     <<<1,  TB, 0, stream>>>(btot, 256);
  kb_count   <<<GB, TB, 0, stream>>>(dstp, btot);
  kb_bscan   <<<1,  TB, 0, stream>>>(btot, bbase, bcur);
  kb_scatter <<<GB, TB, 0, stream>>>(srcp, dstp, bcur, buf);
  kb_finalize<<<NB, TB, 0, stream>>>(buf, btot, bbase, offs, cnt, srcs);

  // ---- layer 1 ----
  k_gemm<<<gRow, TB, 0, stream>>>(node_x, W1, Hbf, flagp, 1);
  k_sd  <<<gWav, TB, 0, stream>>>(Hbf, as1, ad1, Sv, Dv, flagp);
  k_agg <<<gWav, TB, 0, stream>>>(Hbf, Sv, Dv, offs, cnt, srcs, b1, Abf, 1, flagp);

  // ---- layer 2 ----
  k_gemm<<<gRow, TB, 0, stream>>>(Abf, W2, Hbf, flagp, 0);
  k_sd  <<<gWav, TB, 0, stream>>>(Hbf, as2, ad2, Sv, Dv, flagp);
  k_agg <<<gWav, TB, 0, stream>>>(Hbf, Sv, Dv, offs, cnt, srcs, b2, Abf, 0, flagp);

  // ---- output projection ----
  k_out <<<gRow, TB, 0, stream>>>(Abf, Wo, bo, d_out, flagp);
}

// Round 5
// 430.089 us; speedup vs baseline: 1.5348x; 1.0601x over previous
//
#include <hip/hip_runtime.h>
#include <hip/hip_bf16.h>

typedef unsigned short u16;
typedef unsigned int   u32;

#define NN 50000
#define EE 1600000
#define DD 128
#define DYY 64
#define NB 196      // dst buckets: dst>>8
#define EPB 8192    // edges per bucketing block
#define GB 196      // ceil(EE/EPB)
#define MAXD 160    // per-wave LDS edge cache (Poisson(32) max deg << 160)

typedef __attribute__((ext_vector_type(8))) short bf16x8;
typedef __attribute__((ext_vector_type(4))) float f32x4;

__device__ __forceinline__ float bf2f(u32 u){ return __uint_as_float(u << 16); }
__device__ __forceinline__ u16 f2bf(float f){
  u32 u = __float_as_uint(f);
  u += 0x7FFFu + ((u >> 16) & 1u);   // round-to-nearest-even
  return (u16)(u >> 16);
}
// adaptive scalar load: isbf ? bf16[i] : fp32[i]
__device__ __forceinline__ float ldv(const void* p, int i, int isbf){
  return isbf ? bf2f((u32)((const u16*)p)[i]) : ((const float*)p)[i];
}

__device__ __forceinline__ float wave_sum(float v){
  #pragma unroll
  for (int s = 32; s; s >>= 1) v += __shfl_xor(v, s, 64);
  return v;
}
__device__ __forceinline__ float wave_max(float v){
  #pragma unroll
  for (int s = 32; s; s >>= 1) v = fmaxf(v, __shfl_xor(v, s, 64));
  return v;
}

// dtype probe on W1 (proved fp32 in round 3; kept for robustness)
__global__ void k_detect(const u32* __restrict__ w1, int* __restrict__ flagp){
  __shared__ int cnt_s;
  if (threadIdx.x == 0) cnt_s = 0;
  __syncthreads();
  int c = 0;
  for (int i = threadIdx.x; i < 2048; i += 256){
    u32 b = (w1[i] >> 7) & 0xFFu;
    if (b >= 100u && b <= 130u) c++;
  }
  atomicAdd(&cnt_s, c);
  __syncthreads();
  if (threadIdx.x == 0) *flagp = (cnt_s > 1600) ? 1 : 0;
}

__global__ void k_zero(int* __restrict__ p, int n){
  int i = blockIdx.x * blockDim.x + threadIdx.x;
  if (i < n) p[i] = 0;
}

// ---- CSR build: locality-aware counting sort by dst ----
__global__ __launch_bounds__(256) void kb_count(const int* __restrict__ dst, int* __restrict__ btot){
  __shared__ int hist[256];
  int tid = threadIdx.x;
  hist[tid] = 0;
  __syncthreads();
  int e0 = blockIdx.x * EPB, e1 = min(e0 + EPB, EE);
  for (int e = e0 + tid; e < e1; e += 256) atomicAdd(&hist[dst[e] >> 8], 1);
  __syncthreads();
  if (tid < NB && hist[tid]) atomicAdd(&btot[tid], hist[tid]);
}

__global__ void kb_bscan(const int* __restrict__ btot, int* __restrict__ bbase, int* __restrict__ bcur){
  __shared__ int sd[256];
  int tid = threadIdx.x;
  int v = (tid < NB) ? btot[tid] : 0;
  sd[tid] = v;
  __syncthreads();
  for (int o = 1; o < 256; o <<= 1){
    int t = (tid >= o) ? sd[tid - o] : 0;
    __syncthreads();
    sd[tid] += t;
    __syncthreads();
  }
  if (tid < NB){ bbase[tid] = sd[tid] - v; bcur[tid] = sd[tid] - v; }
}

__global__ __launch_bounds__(256) void kb_scatter(const int* __restrict__ src, const int* __restrict__ dst,
                                                  int* __restrict__ bcur, u32* __restrict__ buf){
  __shared__ int hist[256];
  __shared__ int lcur[256];
  int tid = threadIdx.x;
  hist[tid] = 0;
  __syncthreads();
  int e0 = blockIdx.x * EPB, e1 = min(e0 + EPB, EE);
  for (int e = e0 + tid; e < e1; e += 256) atomicAdd(&hist[dst[e] >> 8], 1);
  __syncthreads();
  if (tid < NB && hist[tid]) lcur[tid] = atomicAdd(&bcur[tid], hist[tid]);
  __syncthreads();
  for (int e = e0 + tid; e < e1; e += 256){
    int d = dst[e];
    int pos = atomicAdd(&lcur[d >> 8], 1);
    buf[pos] = (u32)src[e] | ((u32)(d & 255) << 16);
  }
}

__global__ __launch_bounds__(256) void kb_finalize(const u32* __restrict__ buf,
                                                   const int* __restrict__ btot, const int* __restrict__ bbase,
                                                   int* __restrict__ offs, int* __restrict__ cnt,
                                                   u16* __restrict__ srcs){
  __shared__ int dh[256];
  __shared__ int sd[256];
  __shared__ int dcur[256];
  int tid = threadIdx.x, b = blockIdx.x;
  int n = btot[b], base = bbase[b];
  dh[tid] = 0;
  __syncthreads();
  for (int i = tid; i < n; i += 256) atomicAdd(&dh[(buf[base + i] >> 16) & 255], 1);
  __syncthreads();
  int v = dh[tid];
  sd[tid] = v;
  __syncthreads();
  for (int o = 1; o < 256; o <<= 1){
    int t = (tid >= o) ? sd[tid - o] : 0;
    __syncthreads();
    sd[tid] += t;
    __syncthreads();
  }
  int excl = sd[tid] - v;
  dcur[tid] = base + excl;
  int d = (b << 8) + tid;
  if (d < NN){ offs[d] = base + excl; cnt[d] = v; }
  __syncthreads();
  for (int i = tid; i < n; i += 256){
    u32 u = buf[base + i];
    int pos = atomicAdd(&dcur[(u >> 16) & 255], 1);
    srcs[pos] = (u16)(u & 0xffffu);
  }
}

// MFMA GEMM: H[r][c] = sum_k X[r][k]*W[k][c], 64 rows/block, bf16 MFMA 16x16x32.
// Fused epilogue: Sv[r] = h.att_src, Dv[r] = h.att_dst from fp32 accumulators.
// LDS tiles XOR-swizzled (16B blocks) for conflict-free ds_read_b128.
__global__ __launch_bounds__(256) void k_gemm(const void* __restrict__ X,
                                              const void* __restrict__ W,
                                              u16* __restrict__ Hout,
                                              const void* __restrict__ as,
                                              const void* __restrict__ ad,
                                              float* __restrict__ Sv, float* __restrict__ Dv,
                                              const int* __restrict__ flagp, int xext){
  __shared__ uint4 Xs4[64 * 16];    // 64 rows x 256 B (swizzled bf16)   16 KB
  __shared__ uint4 Wt4[128 * 16];   // 128 cols x 256 B (transposed)     32 KB
  u16* Xs = (u16*)Xs4;
  u16* Wt = (u16*)Wt4;
  int isbf = *flagp;
  int xbf = xext ? isbf : 1;        // internal buffers always bf16
  int tid = threadIdx.x;
  int row0 = blockIdx.x * 64;
  // stage Wt[col][k] (transposed, swizzled)
  for (int i = tid; i < DD * DD; i += 256){
    int k = i >> 7, col = i & 127;
    float w = isbf ? bf2f((u32)((const u16*)W)[i]) : ((const float*)W)[i];
    int bo = col * 256 + ((2 * k) ^ ((col & 7) << 4));
    Wt[bo >> 1] = f2bf(w);
  }
  // stage Xs[r][c] (swizzled, zero-pad past NN)
  for (int i = tid; i < 64 * DD; i += 256){
    int r = i >> 7, c = i & 127;
    int gr = row0 + r;
    float x = 0.f;
    if (gr < NN) x = xbf ? bf2f((u32)((const u16*)X)[(size_t)gr * DD + c])
                         : ((const float*)X)[(size_t)gr * DD + c];
    int bo = r * 256 + ((2 * c) ^ ((r & 7) << 4));
    Xs[bo >> 1] = f2bf(x);
  }
  __syncthreads();
  int wv = tid >> 6, lane = tid & 63;
  int n = lane & 15, q = lane >> 4;
  int rsl = wv * 16;                 // wave's row slice within block
  f32x4 acc[8];
  #pragma unroll
  for (int t = 0; t < 8; ++t) acc[t] = (f32x4){0.f, 0.f, 0.f, 0.f};
  union F8 { uint4 u; bf16x8 v; };
  #pragma unroll
  for (int ks = 0; ks < 4; ++ks){
    int kb = ks * 64 + q * 16;       // byte offset of this lane's 8-elem k chunk
    int ar = rsl + n;                // A row (m = lane&15)
    F8 a; a.u = *(const uint4*)((const char*)Xs4 + ar * 256 + (kb ^ ((ar & 7) << 4)));
    #pragma unroll
    for (int t = 0; t < 8; ++t){
      int col = t * 16 + n;          // B col (n = lane&15)
      F8 b; b.u = *(const uint4*)((const char*)Wt4 + col * 256 + (kb ^ ((col & 7) << 4)));
      acc[t] = __builtin_amdgcn_mfma_f32_16x16x32_bf16(a.v, b.v, acc[t], 0, 0, 0);
    }
  }
  // epilogue: Sv/Dv partials (lane holds rows q*4+rg, col t*16+n)
  float ps[4] = {0, 0, 0, 0}, pd[4] = {0, 0, 0, 0};
  #pragma unroll
  for (int t = 0; t < 8; ++t){
    float a_s = ldv(as, t * 16 + n, isbf);
    float a_d = ldv(ad, t * 16 + n, isbf);
    #pragma unroll
    for (int rg = 0; rg < 4; ++rg){
      ps[rg] += acc[t][rg] * a_s;
      pd[rg] += acc[t][rg] * a_d;
    }
  }
  #pragma unroll
  for (int rg = 0; rg < 4; ++rg){
    #pragma unroll
    for (int s = 1; s < 16; s <<= 1){
      ps[rg] += __shfl_xor(ps[rg], s, 64);
      pd[rg] += __shfl_xor(pd[rg], s, 64);
    }
  }
  #pragma unroll
  for (int rg = 0; rg < 4; ++rg){
    int grow = row0 + rsl + q * 4 + rg;
    if (grow < NN){
      if (n == 0){ Sv[grow] = ps[rg]; Dv[grow] = pd[rg]; }
      #pragma unroll
      for (int t = 0; t < 8; ++t)
        Hout[(size_t)grow * DD + t * 16 + n] = f2bf(acc[t][rg]);
    }
  }
}

// one wave per destination: phase A computes softmax weights into LDS (no global
// dependency chain left in gather loop); phase B pure row gather + FMA.
__global__ __launch_bounds__(256) void k_agg(const u16* __restrict__ H,
                                             const float* __restrict__ Sv, const float* __restrict__ Dv,
                                             const int* __restrict__ offs, const int* __restrict__ cnt,
                                             const u16* __restrict__ srcs,
                                             const void* __restrict__ bias,
                                             u16* __restrict__ Xout, int do_relu,
                                             const int* __restrict__ flagp){
  __shared__ int   s_i[4][MAXD];
  __shared__ float s_w[4][MAXD];
  int isbf = *flagp;
  int gid = blockIdx.x * blockDim.x + threadIdx.x;
  int wid = gid >> 6, lane = gid & 63;
  int wv = threadIdx.x >> 6;
  if (wid >= NN) return;
  int off = offs[wid], c = cnt[wid];
  float dvw = Dv[wid];
  float eself = fmaxf(Sv[wid] + dvw, 0.f);
  // phase A: gather source logits, stash (sidx, s) in LDS, running max
  float mS = -1e30f;
  for (int j = lane; j < c; j += 64){
    int sidx = (int)srcs[off + j];
    float s = Sv[sidx];
    if (j < MAXD){ s_i[wv][j] = sidx; s_w[wv][j] = s; }
    mS = fmaxf(mS, s);
  }
  mS = wave_max(mS);
  // relu monotone: max_j relu(s_j+d) = relu(max_j s_j + d); self >= 0 covers c==0
  float m = fmaxf(eself, fmaxf(mS + dvw, 0.f));
  float wself = __expf(eself - m);
  int cf = min(c, MAXD);
  float dl = 0.f;
  for (int j = lane; j < cf; j += 64){
    float wgt = __expf(fmaxf(s_w[wv][j] + dvw, 0.f) - m);
    s_w[wv][j] = wgt;
    dl += wgt;
  }
  int grp = lane >> 4, cg = lane & 15;
  const u32* H32 = (const u32*)H;
  float acc[8] = {0, 0, 0, 0, 0, 0, 0, 0};
  if (grp == 0){
    uint4 r = *(const uint4*)(H32 + (size_t)wid * 64 + cg * 4);
    acc[0] = wself * bf2f(r.x & 0xffffu); acc[1] = wself * bf2f(r.x >> 16);
    acc[2] = wself * bf2f(r.y & 0xffffu); acc[3] = wself * bf2f(r.y >> 16);
    acc[4] = wself * bf2f(r.z & 0xffffu); acc[5] = wself * bf2f(r.z >> 16);
    acc[6] = wself * bf2f(r.w & 0xffffu); acc[7] = wself * bf2f(r.w >> 16);
  }
  // phase B: pure gather — weights from LDS, rows independent dwordx4 loads
  for (int base = 0; base < cf; base += 4){
    int j = base + grp;
    float wgt = 0.f; int sidx = 0;
    if (j < cf){ wgt = s_w[wv][j]; sidx = s_i[wv][j]; }
    uint4 r = *(const uint4*)(H32 + (size_t)sidx * 64 + cg * 4);
    acc[0] += wgt * bf2f(r.x & 0xffffu); acc[1] += wgt * bf2f(r.x >> 16);
    acc[2] += wgt * bf2f(r.y & 0xffffu); acc[3] += wgt * bf2f(r.y >> 16);
    acc[4] += wgt * bf2f(r.z & 0xffffu); acc[5] += wgt * bf2f(r.z >> 16);
    acc[6] += wgt * bf2f(r.w & 0xffffu); acc[7] += wgt * bf2f(r.w >> 16);
  }
  // ultra-rare tail (deg > MAXD): recompute weights on the fly
  for (int base = MAXD; base < c; base += 4){
    int j = base + grp;
    bool valid = j < c;
    int sidx = valid ? (int)srcs[off + j] : 0;
    float e = fmaxf(Sv[sidx] + dvw, 0.f);
    float wgt = valid ? __expf(e - m) : 0.f;
    if (cg == 0) dl += wgt;
    uint4 r = *(const uint4*)(H32 + (size_t)sidx * 64 + cg * 4);
    acc[0] += wgt * bf2f(r.x & 0xffffu); acc[1] += wgt * bf2f(r.x >> 16);
    acc[2] += wgt * bf2f(r.y & 0xffffu); acc[3] += wgt * bf2f(r.y >> 16);
    acc[4] += wgt * bf2f(r.z & 0xffffu); acc[5] += wgt * bf2f(r.z >> 16);
    acc[6] += wgt * bf2f(r.w & 0xffffu); acc[7] += wgt * bf2f(r.w >> 16);
  }
  #pragma unroll
  for (int i = 0; i < 8; ++i){
    acc[i] += __shfl_xor(acc[i], 16, 64);
    acc[i] += __shfl_xor(acc[i], 32, 64);
  }
  float denom = wave_sum(dl) + wself;  // >= wself > 0
  float inv = 1.f / denom;
  if (grp == 0){
    uint4 pk;
    u32* pkp = (u32*)&pk;
    #pragma unroll
    for (int qq = 0; qq < 4; ++qq){
      float o0 = acc[2 * qq]     * inv + ldv(bias, cg * 8 + 2 * qq,     isbf);
      float o1 = acc[2 * qq + 1] * inv + ldv(bias, cg * 8 + 2 * qq + 1, isbf);
      if (do_relu){ o0 = fmaxf(o0, 0.f); o1 = fmaxf(o1, 0.f); }
      pkp[qq] = ((u32)f2bf(o1) << 16) | (u32)f2bf(o0);
    }
    *(uint4*)((u32*)Xout + (size_t)wid * 64 + cg * 4) = pk;
  }
}

// out[row][col] = sum_k X[row][k]*Wout[k][col] + b[col]; store dtype per input flavor
__global__ __launch_bounds__(256) void k_out(const u16* __restrict__ X,
                                             const void* __restrict__ W,
                                             const void* __restrict__ b,
                                             void* __restrict__ out,
                                             const int* __restrict__ flagp){
  __shared__ float Ws[DD * DYY];  // 32 KB
  __shared__ float Xs[16 * DD];   // 8 KB
  int isbf = *flagp;
  int tid = threadIdx.x;
  if (isbf){
    const u32* Wv = (const u32*)W;
    for (int k = tid; k < DD * DYY / 2; k += 256){
      u32 u = Wv[k];
      Ws[2 * k]     = bf2f(u & 0xffffu);
      Ws[2 * k + 1] = bf2f(u >> 16);
    }
  } else {
    const float* Wf = (const float*)W;
    for (int k = tid; k < DD * DYY; k += 256) Ws[k] = Wf[k];
  }
  int row0 = blockIdx.x * 16;
  const u32* Xv = (const u32*)(X + (size_t)row0 * DD);
  for (int idx = tid; idx < 16 * DD / 2; idx += 256){
    u32 u = Xv[idx];
    Xs[2 * idx]     = bf2f(u & 0xffffu);
    Xs[2 * idx + 1] = bf2f(u >> 16);
  }
  __syncthreads();
  int col = tid & 63;
  int rb  = (tid >> 6) * 4;
  float acc[4] = {0, 0, 0, 0};
  for (int k = 0; k < DD; ++k){
    float w = Ws[k * DYY + col];
    #pragma unroll
    for (int rr = 0; rr < 4; ++rr) acc[rr] += Xs[(rb + rr) * DD + k] * w;
  }
  float bo = ldv(b, col, isbf);
  #pragma unroll
  for (int rr = 0; rr < 4; ++rr){
    float v = acc[rr] + bo;
    size_t oi = (size_t)(row0 + rb + rr) * DYY + col;
    if (isbf) ((u16*)out)[oi] = f2bf(v);
    else      ((float*)out)[oi] = v;
  }
}

extern "C" void kernel_launch(void* const* d_in, const int* in_sizes, int n_in,
                              void* d_out, int out_size, void* d_ws, size_t ws_size,
                              hipStream_t stream) {
  const void* node_x = d_in[0];
  const int* ei   = (const int*)d_in[1];
  const int* srcp = ei;
  const int* dstp = ei + EE;
  const void* W1  = d_in[2];
  const void* as1 = d_in[3];
  const void* ad1 = d_in[4];
  const void* b1  = d_in[5];
  const void* W2  = d_in[6];
  const void* as2 = d_in[7];
  const void* ad2 = d_in[8];
  const void* b2  = d_in[9];
  const void* Wo  = d_in[10];
  const void* bo  = d_in[11];

  // workspace carve: ~30 MB. buf aliases Abf (dead until first k_agg write).
  char* w = (char*)d_ws;
  u16*   Hbf  = (u16*)w;   w += (size_t)NN * DD * 2;  // 12.8 MB
  u16*   Abf  = (u16*)w;   w += (size_t)NN * DD * 2;  // 12.8 MB (aliased by buf during CSR build)
  u32*   buf  = (u32*)Abf;                             // 6.4 MB, fits in Abf
  float* Sv   = (float*)w; w += (size_t)NN * 4;
  float* Dv   = (float*)w; w += (size_t)NN * 4;
  int*   cnt  = (int*)w;   w += (size_t)NN * 4;
  int*   offs = (int*)w;   w += (size_t)NN * 4;
  int*   flagp= (int*)w;   w += 16;
  int*   btot = (int*)w;   w += 1024;
  int*   bbase= (int*)w;   w += 1024;
  int*   bcur = (int*)w;   w += 1024;
  u16*   srcs = (u16*)w;   w += (size_t)EE * 2;       // 3.2 MB

  const int TB = 256;
  const int gWav = (NN * 64) / TB;       // 12500 (one wave per node)
  const int gMM  = (NN + 63) / 64;       // 782  (64 rows per MFMA gemm block)
  const int gRow = NN / 16;              // 3125 (k_out)

  // dtype probe + CSR build (topology-only, shared by both layers)
  k_detect   <<<1,  TB, 0, stream>>>((const u32*)W1, flagp);
  k_zero     <<<1,  TB, 0, stream>>>(btot, 256);
  kb_count   <<<GB, TB, 0, stream>>>(dstp, btot);
  kb_bscan   <<<1,  TB, 0, stream>>>(btot, bbase, bcur);
  kb_scatter <<<GB, TB, 0, stream>>>(srcp, dstp, bcur, buf);
  kb_finalize<<<NB, TB, 0, stream>>>(buf, btot, bbase, offs, cnt, srcs);

  // ---- layer 1 ----
  k_gemm<<<gMM,  TB, 0, stream>>>(node_x, W1, Hbf, as1, ad1, Sv, Dv, flagp, 1);
  k_agg <<<gWav, TB, 0, stream>>>(Hbf, Sv, Dv, offs, cnt, srcs, b1, Abf, 1, flagp);

  // ---- layer 2 ----
  k_gemm<<<gMM,  TB, 0, stream>>>(Abf, W2, Hbf, as2, ad2, Sv, Dv, flagp, 0);
  k_agg <<<gWav, TB, 0, stream>>>(Hbf, Sv, Dv, offs, cnt, srcs, b2, Abf, 0, flagp);

  // ---- output projection ----
  k_out <<<gRow, TB, 0, stream>>>(Abf, Wo, bo, d_out, flagp);
}

// Round 6
// 338.890 us; speedup vs baseline: 1.9478x; 1.2691x over previous
//
#include <hip/hip_runtime.h>
#include <hip/hip_bf16.h>

typedef unsigned short u16;
typedef unsigned int   u32;

#define NN 50000
#define EE 1600000
#define DD 128
#define DYY 64
#define NB 196      // dst buckets: dst>>8
#define EPB 8192    // edges per bucketing block
#define GB 196      // ceil(EE/EPB)
#define MAXD 160    // per-wave LDS edge cache (Poisson(32) max deg << 160)
#define NTILE 3125  // 50000 / 16 row-tiles (exact)

typedef __attribute__((ext_vector_type(8))) short bf16x8;
typedef __attribute__((ext_vector_type(4))) float f32x4;

__device__ __forceinline__ float bf2f(u32 u){ return __uint_as_float(u << 16); }
__device__ __forceinline__ u16 f2bf(float f){
  u32 u = __float_as_uint(f);
  u += 0x7FFFu + ((u >> 16) & 1u);   // round-to-nearest-even
  return (u16)(u >> 16);
}
// adaptive scalar load: isbf ? bf16[i] : fp32[i]
__device__ __forceinline__ float ldv(const void* p, int i, int isbf){
  return isbf ? bf2f((u32)((const u16*)p)[i]) : ((const float*)p)[i];
}

__device__ __forceinline__ float wave_sum(float v){
  #pragma unroll
  for (int s = 32; s; s >>= 1) v += __shfl_xor(v, s, 64);
  return v;
}
__device__ __forceinline__ float wave_max(float v){
  #pragma unroll
  for (int s = 32; s; s >>= 1) v = fmaxf(v, __shfl_xor(v, s, 64));
  return v;
}

// dtype probe on W1 (proved fp32 in round 3; kept for robustness)
__global__ void k_detect(const u32* __restrict__ w1, int* __restrict__ flagp){
  __shared__ int cnt_s;
  if (threadIdx.x == 0) cnt_s = 0;
  __syncthreads();
  int c = 0;
  for (int i = threadIdx.x; i < 2048; i += 256){
    u32 b = (w1[i] >> 7) & 0xFFu;
    if (b >= 100u && b <= 130u) c++;
  }
  atomicAdd(&cnt_s, c);
  __syncthreads();
  if (threadIdx.x == 0) *flagp = (cnt_s > 1600) ? 1 : 0;
}

__global__ void k_zero(int* __restrict__ p, int n){
  int i = blockIdx.x * blockDim.x + threadIdx.x;
  if (i < n) p[i] = 0;
}

// ---- CSR build: locality-aware counting sort by dst ----
__global__ __launch_bounds__(256) void kb_count(const int* __restrict__ dst, int* __restrict__ btot){
  __shared__ int hist[256];
  int tid = threadIdx.x;
  hist[tid] = 0;
  __syncthreads();
  int e0 = blockIdx.x * EPB, e1 = min(e0 + EPB, EE);
  for (int e = e0 + tid; e < e1; e += 256) atomicAdd(&hist[dst[e] >> 8], 1);
  __syncthreads();
  if (tid < NB && hist[tid]) atomicAdd(&btot[tid], hist[tid]);
}

__global__ void kb_bscan(const int* __restrict__ btot, int* __restrict__ bbase, int* __restrict__ bcur){
  __shared__ int sd[256];
  int tid = threadIdx.x;
  int v = (tid < NB) ? btot[tid] : 0;
  sd[tid] = v;
  __syncthreads();
  for (int o = 1; o < 256; o <<= 1){
    int t = (tid >= o) ? sd[tid - o] : 0;
    __syncthreads();
    sd[tid] += t;
    __syncthreads();
  }
  if (tid < NB){ bbase[tid] = sd[tid] - v; bcur[tid] = sd[tid] - v; }
}

__global__ __launch_bounds__(256) void kb_scatter(const int* __restrict__ src, const int* __restrict__ dst,
                                                  int* __restrict__ bcur, u32* __restrict__ buf){
  __shared__ int hist[256];
  __shared__ int lcur[256];
  int tid = threadIdx.x;
  hist[tid] = 0;
  __syncthreads();
  int e0 = blockIdx.x * EPB, e1 = min(e0 + EPB, EE);
  for (int e = e0 + tid; e < e1; e += 256) atomicAdd(&hist[dst[e] >> 8], 1);
  __syncthreads();
  if (tid < NB && hist[tid]) lcur[tid] = atomicAdd(&bcur[tid], hist[tid]);
  __syncthreads();
  for (int e = e0 + tid; e < e1; e += 256){
    int d = dst[e];
    int pos = atomicAdd(&lcur[d >> 8], 1);
    buf[pos] = (u32)src[e] | ((u32)(d & 255) << 16);
  }
}

__global__ __launch_bounds__(256) void kb_finalize(const u32* __restrict__ buf,
                                                   const int* __restrict__ btot, const int* __restrict__ bbase,
                                                   int* __restrict__ offs, int* __restrict__ cnt,
                                                   u16* __restrict__ srcs){
  __shared__ int dh[256];
  __shared__ int sd[256];
  __shared__ int dcur[256];
  int tid = threadIdx.x, b = blockIdx.x;
  int n = btot[b], base = bbase[b];
  dh[tid] = 0;
  __syncthreads();
  for (int i = tid; i < n; i += 256) atomicAdd(&dh[(buf[base + i] >> 16) & 255], 1);
  __syncthreads();
  int v = dh[tid];
  sd[tid] = v;
  __syncthreads();
  for (int o = 1; o < 256; o <<= 1){
    int t = (tid >= o) ? sd[tid - o] : 0;
    __syncthreads();
    sd[tid] += t;
    __syncthreads();
  }
  int excl = sd[tid] - v;
  dcur[tid] = base + excl;
  int d = (b << 8) + tid;
  if (d < NN){ offs[d] = base + excl; cnt[d] = v; }
  __syncthreads();
  for (int i = tid; i < n; i += 256){
    u32 u = buf[base + i];
    int pos = atomicAdd(&dcur[(u >> 16) & 255], 1);
    srcs[pos] = (u16)(u & 0xffffu);
  }
}

// one-time: rewrite W (any dtype) into per-lane MFMA B-fragment layout:
// Wf[((ks*8+t)*64+lane)*8 + j] = bf16 W[ks*32+(lane>>4)*8+j][t*16+(lane&15)]
__global__ void kp_wfrag(const void* __restrict__ W, u16* __restrict__ Wf,
                         const int* __restrict__ flagp){
  int isbf = *flagp;
  int s = blockIdx.x * 64 + threadIdx.x;   // 32 blocks x 64 = 2048 slots
  if (s >= 2048) return;
  int ks = s >> 9, t = (s >> 6) & 7, lane = s & 63;
  int q = lane >> 4, n = lane & 15;
  u16 tmp[8];
  #pragma unroll
  for (int j = 0; j < 8; ++j)
    tmp[j] = f2bf(ldv(W, (ks * 32 + q * 8 + j) * DD + t * 16 + n, isbf));
  *(uint4*)(Wf + (size_t)s * 8) = *(const uint4*)tmp;
}

// MFMA GEMM: H = X·W, one wave per 16-row tile, W pre-formatted fragments in LDS,
// A-fragments straight from global (16B contiguous per lane). Fused Sv/Dv epilogue.
__global__ __launch_bounds__(256) void k_gemm(const void* __restrict__ X,
                                              const u16* __restrict__ Wf,
                                              u16* __restrict__ Hout,
                                              const void* __restrict__ as,
                                              const void* __restrict__ ad,
                                              float* __restrict__ Sv, float* __restrict__ Dv,
                                              const int* __restrict__ flagp, int xext){
  __shared__ uint4 Wl[2048];   // 32 KB
  int isbf = *flagp;
  int xbf = xext ? isbf : 1;   // internal buffers always bf16
  int tid = threadIdx.x;
  const uint4* Wg = (const uint4*)Wf;
  #pragma unroll
  for (int i = 0; i < 8; ++i) Wl[tid + 256 * i] = Wg[tid + 256 * i];
  __syncthreads();
  int wv = tid >> 6, lane = tid & 63;
  int rtile = blockIdx.x * 4 + wv;
  if (rtile >= NTILE) return;        // no barriers after this point
  int q = lane >> 4, n = lane & 15;
  int arow = rtile * 16 + n;         // A row (m = lane&15)
  f32x4 acc[8];
  #pragma unroll
  for (int t = 0; t < 8; ++t) acc[t] = (f32x4){0.f, 0.f, 0.f, 0.f};
  union F8 { uint4 u; bf16x8 v; u16 h[8]; };
  #pragma unroll
  for (int ks = 0; ks < 4; ++ks){
    int kb = ks * 32 + q * 8;        // lane's 8-elem k-chunk
    F8 a;
    if (xbf){
      a.u = *(const uint4*)((const u16*)X + (size_t)arow * DD + kb);
    } else {
      const float* xp = (const float*)X + (size_t)arow * DD + kb;
      float4 f0 = *(const float4*)xp;
      float4 f1 = *(const float4*)(xp + 4);
      a.h[0] = f2bf(f0.x); a.h[1] = f2bf(f0.y); a.h[2] = f2bf(f0.z); a.h[3] = f2bf(f0.w);
      a.h[4] = f2bf(f1.x); a.h[5] = f2bf(f1.y); a.h[6] = f2bf(f1.z); a.h[7] = f2bf(f1.w);
    }
    #pragma unroll
    for (int t = 0; t < 8; ++t){
      F8 b; b.u = Wl[(ks * 8 + t) * 64 + lane];
      acc[t] = __builtin_amdgcn_mfma_f32_16x16x32_bf16(a.v, b.v, acc[t], 0, 0, 0);
    }
  }
  // epilogue: Sv/Dv partials (lane holds rows q*4+rg, col t*16+n) — verified r5
  float ps[4] = {0, 0, 0, 0}, pd[4] = {0, 0, 0, 0};
  #pragma unroll
  for (int t = 0; t < 8; ++t){
    float a_s = ldv(as, t * 16 + n, isbf);
    float a_d = ldv(ad, t * 16 + n, isbf);
    #pragma unroll
    for (int rg = 0; rg < 4; ++rg){
      ps[rg] += acc[t][rg] * a_s;
      pd[rg] += acc[t][rg] * a_d;
    }
  }
  #pragma unroll
  for (int rg = 0; rg < 4; ++rg){
    #pragma unroll
    for (int s = 1; s < 16; s <<= 1){
      ps[rg] += __shfl_xor(ps[rg], s, 64);
      pd[rg] += __shfl_xor(pd[rg], s, 64);
    }
  }
  #pragma unroll
  for (int rg = 0; rg < 4; ++rg){
    int grow = rtile * 16 + q * 4 + rg;   // always < NN (50000 = 3125*16)
    if (n == 0){ Sv[grow] = ps[rg]; Dv[grow] = pd[rg]; }
    #pragma unroll
    for (int t = 0; t < 8; ++t)
      Hout[(size_t)grow * DD + t * 16 + n] = f2bf(acc[t][rg]);
  }
}

// one wave per destination: phase A softmax weights into LDS; phase B pure gather.
__global__ __launch_bounds__(256) void k_agg(const u16* __restrict__ H,
                                             const float* __restrict__ Sv, const float* __restrict__ Dv,
                                             const int* __restrict__ offs, const int* __restrict__ cnt,
                                             const u16* __restrict__ srcs,
                                             const void* __restrict__ bias,
                                             u16* __restrict__ Xout, int do_relu,
                                             const int* __restrict__ flagp){
  __shared__ int   s_i[4][MAXD];
  __shared__ float s_w[4][MAXD];
  int isbf = *flagp;
  int gid = blockIdx.x * blockDim.x + threadIdx.x;
  int wid = gid >> 6, lane = gid & 63;
  int wv = threadIdx.x >> 6;
  if (wid >= NN) return;
  int off = offs[wid], c = cnt[wid];
  float dvw = Dv[wid];
  float eself = fmaxf(Sv[wid] + dvw, 0.f);
  float mS = -1e30f;
  for (int j = lane; j < c; j += 64){
    int sidx = (int)srcs[off + j];
    float s = Sv[sidx];
    if (j < MAXD){ s_i[wv][j] = sidx; s_w[wv][j] = s; }
    mS = fmaxf(mS, s);
  }
  mS = wave_max(mS);
  float m = fmaxf(eself, fmaxf(mS + dvw, 0.f));
  float wself = __expf(eself - m);
  int cf = min(c, MAXD);
  float dl = 0.f;
  for (int j = lane; j < cf; j += 64){
    float wgt = __expf(fmaxf(s_w[wv][j] + dvw, 0.f) - m);
    s_w[wv][j] = wgt;
    dl += wgt;
  }
  int grp = lane >> 4, cg = lane & 15;
  const u32* H32 = (const u32*)H;
  float acc[8] = {0, 0, 0, 0, 0, 0, 0, 0};
  if (grp == 0){
    uint4 r = *(const uint4*)(H32 + (size_t)wid * 64 + cg * 4);
    acc[0] = wself * bf2f(r.x & 0xffffu); acc[1] = wself * bf2f(r.x >> 16);
    acc[2] = wself * bf2f(r.y & 0xffffu); acc[3] = wself * bf2f(r.y >> 16);
    acc[4] = wself * bf2f(r.z & 0xffffu); acc[5] = wself * bf2f(r.z >> 16);
    acc[6] = wself * bf2f(r.w & 0xffffu); acc[7] = wself * bf2f(r.w >> 16);
  }
  for (int base = 0; base < cf; base += 4){
    int j = base + grp;
    float wgt = 0.f; int sidx = 0;
    if (j < cf){ wgt = s_w[wv][j]; sidx = s_i[wv][j]; }
    uint4 r = *(const uint4*)(H32 + (size_t)sidx * 64 + cg * 4);
    acc[0] += wgt * bf2f(r.x & 0xffffu); acc[1] += wgt * bf2f(r.x >> 16);
    acc[2] += wgt * bf2f(r.y & 0xffffu); acc[3] += wgt * bf2f(r.y >> 16);
    acc[4] += wgt * bf2f(r.z & 0xffffu); acc[5] += wgt * bf2f(r.z >> 16);
    acc[6] += wgt * bf2f(r.w & 0xffffu); acc[7] += wgt * bf2f(r.w >> 16);
  }
  for (int base = MAXD; base < c; base += 4){   // ultra-rare tail
    int j = base + grp;
    bool valid = j < c;
    int sidx = valid ? (int)srcs[off + j] : 0;
    float e = fmaxf(Sv[sidx] + dvw, 0.f);
    float wgt = valid ? __expf(e - m) : 0.f;
    if (cg == 0) dl += wgt;
    uint4 r = *(const uint4*)(H32 + (size_t)sidx * 64 + cg * 4);
    acc[0] += wgt * bf2f(r.x & 0xffffu); acc[1] += wgt * bf2f(r.x >> 16);
    acc[2] += wgt * bf2f(r.y & 0xffffu); acc[3] += wgt * bf2f(r.y >> 16);
    acc[4] += wgt * bf2f(r.z & 0xffffu); acc[5] += wgt * bf2f(r.z >> 16);
    acc[6] += wgt * bf2f(r.w & 0xffffu); acc[7] += wgt * bf2f(r.w >> 16);
  }
  #pragma unroll
  for (int i = 0; i < 8; ++i){
    acc[i] += __shfl_xor(acc[i], 16, 64);
    acc[i] += __shfl_xor(acc[i], 32, 64);
  }
  float denom = wave_sum(dl) + wself;
  float inv = 1.f / denom;
  if (grp == 0){
    uint4 pk;
    u32* pkp = (u32*)&pk;
    #pragma unroll
    for (int qq = 0; qq < 4; ++qq){
      float o0 = acc[2 * qq]     * inv + ldv(bias, cg * 8 + 2 * qq,     isbf);
      float o1 = acc[2 * qq + 1] * inv + ldv(bias, cg * 8 + 2 * qq + 1, isbf);
      if (do_relu){ o0 = fmaxf(o0, 0.f); o1 = fmaxf(o1, 0.f); }
      pkp[qq] = ((u32)f2bf(o1) << 16) | (u32)f2bf(o0);
    }
    *(uint4*)((u32*)Xout + (size_t)wid * 64 + cg * 4) = pk;
  }
}

// out = X·Wout + b
__global__ __launch_bounds__(256) void k_out(const u16* __restrict__ X,
                                             const void* __restrict__ W,
                                             const void* __restrict__ b,
                                             void* __restrict__ out,
                                             const int* __restrict__ flagp){
  __shared__ float Ws[DD * DYY];  // 32 KB
  __shared__ float Xs[16 * DD];   // 8 KB
  int isbf = *flagp;
  int tid = threadIdx.x;
  if (isbf){
    const u32* Wv = (const u32*)W;
    for (int k = tid; k < DD * DYY / 2; k += 256){
      u32 u = Wv[k];
      Ws[2 * k]     = bf2f(u & 0xffffu);
      Ws[2 * k + 1] = bf2f(u >> 16);
    }
  } else {
    const float* Wf = (const float*)W;
    for (int k = tid; k < DD * DYY; k += 256) Ws[k] = Wf[k];
  }
  int row0 = blockIdx.x * 16;
  const u32* Xv = (const u32*)(X + (size_t)row0 * DD);
  for (int idx = tid; idx < 16 * DD / 2; idx += 256){
    u32 u = Xv[idx];
    Xs[2 * idx]     = bf2f(u & 0xffffu);
    Xs[2 * idx + 1] = bf2f(u >> 16);
  }
  __syncthreads();
  int col = tid & 63;
  int rb  = (tid >> 6) * 4;
  float acc[4] = {0, 0, 0, 0};
  for (int k = 0; k < DD; ++k){
    float w = Ws[k * DYY + col];
    #pragma unroll
    for (int rr = 0; rr < 4; ++rr) acc[rr] += Xs[(rb + rr) * DD + k] * w;
  }
  float bo = ldv(b, col, isbf);
  #pragma unroll
  for (int rr = 0; rr < 4; ++rr){
    float v = acc[rr] + bo;
    size_t oi = (size_t)(row0 + rb + rr) * DYY + col;
    if (isbf) ((u16*)out)[oi] = f2bf(v);
    else      ((float*)out)[oi] = v;
  }
}

extern "C" void kernel_launch(void* const* d_in, const int* in_sizes, int n_in,
                              void* d_out, int out_size, void* d_ws, size_t ws_size,
                              hipStream_t stream) {
  const void* node_x = d_in[0];
  const int* ei   = (const int*)d_in[1];
  const int* srcp = ei;
  const int* dstp = ei + EE;
  const void* W1  = d_in[2];
  const void* as1 = d_in[3];
  const void* ad1 = d_in[4];
  const void* b1  = d_in[5];
  const void* W2  = d_in[6];
  const void* as2 = d_in[7];
  const void* ad2 = d_in[8];
  const void* b2  = d_in[9];
  const void* Wo  = d_in[10];
  const void* bo  = d_in[11];

  // workspace carve: ~30 MB. buf aliases Abf (dead until first k_agg write).
  char* w = (char*)d_ws;
  u16*   Hbf  = (u16*)w;   w += (size_t)NN * DD * 2;  // 12.8 MB
  u16*   Abf  = (u16*)w;   w += (size_t)NN * DD * 2;  // 12.8 MB (aliased by buf during CSR build)
  u32*   buf  = (u32*)Abf;                             // 6.4 MB, fits in Abf
  float* Sv   = (float*)w; w += (size_t)NN * 4;
  float* Dv   = (float*)w; w += (size_t)NN * 4;
  int*   cnt  = (int*)w;   w += (size_t)NN * 4;
  int*   offs = (int*)w;   w += (size_t)NN * 4;
  int*   flagp= (int*)w;   w += 16;
  int*   btot = (int*)w;   w += 1024;
  int*   bbase= (int*)w;   w += 1024;
  int*   bcur = (int*)w;   w += 1024;
  u16*   srcs = (u16*)w;   w += (size_t)EE * 2;       // 3.2 MB
  u16*   Wf   = (u16*)w;   w += 32768;                // 32 KB fragment-layout W

  const int TB = 256;
  const int gWav = (NN * 64) / TB;       // 12500 (one wave per node)
  const int gMM  = (NTILE + 3) / 4;      // 782 (4 row-tiles per block)
  const int gRow = NN / 16;              // 3125 (k_out)

  // dtype probe + CSR build (topology-only, shared by both layers)
  k_detect   <<<1,  TB, 0, stream>>>((const u32*)W1, flagp);
  k_zero     <<<1,  TB, 0, stream>>>(btot, 256);
  kb_count   <<<GB, TB, 0, stream>>>(dstp, btot);
  kb_bscan   <<<1,  TB, 0, stream>>>(btot, bbase, bcur);
  kb_scatter <<<GB, TB, 0, stream>>>(srcp, dstp, bcur, buf);
  kb_finalize<<<NB, TB, 0, stream>>>(buf, btot, bbase, offs, cnt, srcs);

  // ---- layer 1 ----
  kp_wfrag<<<32,   64, 0, stream>>>(W1, Wf, flagp);
  k_gemm  <<<gMM,  TB, 0, stream>>>(node_x, Wf, Hbf, as1, ad1, Sv, Dv, flagp, 1);
  k_agg   <<<gWav, TB, 0, stream>>>(Hbf, Sv, Dv, offs, cnt, srcs, b1, Abf, 1, flagp);

  // ---- layer 2 ----
  kp_wfrag<<<32,   64, 0, stream>>>(W2, Wf, flagp);
  k_gemm  <<<gMM,  TB, 0, stream>>>(Abf, Wf, Hbf, as2, ad2, Sv, Dv, flagp, 0);
  k_agg   <<<gWav, TB, 0, stream>>>(Hbf, Sv, Dv, offs, cnt, srcs, b2, Abf, 0, flagp);

  // ---- output projection ----
  k_out   <<<gRow, TB, 0, stream>>>(Abf, Wo, bo, d_out, flagp);
}

// Round 7
// 322.406 us; speedup vs baseline: 2.0474x; 1.0511x over previous
//
#include <hip/hip_runtime.h>
#include <hip/hip_bf16.h>
#include <hip/hip_fp16.h>

typedef unsigned short u16;
typedef unsigned int   u32;
typedef _Float16 f16;
typedef __attribute__((ext_vector_type(8))) f16 f16x8;
typedef __attribute__((ext_vector_type(2))) f16 h2;
typedef __attribute__((ext_vector_type(4))) float f32x4;

#define NN 50000
#define EE 1600000
#define DD 128
#define DYY 64
#define NB 196      // dst buckets: dst>>8
#define EPB 8192    // edges per bucketing block
#define GB 196      // ceil(EE/EPB)
#define MAXD 160    // per-wave LDS edge cache (Poisson(32) max deg << 160)
#define NTILE 3125  // 50000 / 16 row-tiles (exact)

__device__ __forceinline__ float bf2f(u32 u){ return __uint_as_float(u << 16); }
__device__ __forceinline__ u16 f2bf(float f){
  u32 u = __float_as_uint(f);
  u += 0x7FFFu + ((u >> 16) & 1u);
  return (u16)(u >> 16);
}
__device__ __forceinline__ u16 f2h(float f){
  union { f16 h; u16 u; } x; x.h = (f16)f; return x.u;
}
// adaptive scalar load: isbf ? bf16[i] : fp32[i]
__device__ __forceinline__ float ldv(const void* p, int i, int isbf){
  return isbf ? bf2f((u32)((const u16*)p)[i]) : ((const float*)p)[i];
}

__device__ __forceinline__ float wave_sum(float v){
  #pragma unroll
  for (int s = 32; s; s >>= 1) v += __shfl_xor(v, s, 64);
  return v;
}
__device__ __forceinline__ float wave_max(float v){
  #pragma unroll
  for (int s = 32; s; s >>= 1) v = fmaxf(v, __shfl_xor(v, s, 64));
  return v;
}

// dtype probe on W1 (proved fp32 in round 3; kept for robustness)
__global__ void k_detect(const u32* __restrict__ w1, int* __restrict__ flagp){
  __shared__ int cnt_s;
  if (threadIdx.x == 0) cnt_s = 0;
  __syncthreads();
  int c = 0;
  for (int i = threadIdx.x; i < 2048; i += 256){
    u32 b = (w1[i] >> 7) & 0xFFu;
    if (b >= 100u && b <= 130u) c++;
  }
  atomicAdd(&cnt_s, c);
  __syncthreads();
  if (threadIdx.x == 0) *flagp = (cnt_s > 1600) ? 1 : 0;
}

__global__ void k_zero(int* __restrict__ p, int n){
  int i = blockIdx.x * blockDim.x + threadIdx.x;
  if (i < n) p[i] = 0;
}

// ---- CSR build: locality-aware counting sort by dst ----
__global__ __launch_bounds__(256) void kb_count(const int* __restrict__ dst, int* __restrict__ btot){
  __shared__ int hist[256];
  int tid = threadIdx.x;
  hist[tid] = 0;
  __syncthreads();
  int e0 = blockIdx.x * EPB, e1 = min(e0 + EPB, EE);
  for (int e = e0 + tid; e < e1; e += 256) atomicAdd(&hist[dst[e] >> 8], 1);
  __syncthreads();
  if (tid < NB && hist[tid]) atomicAdd(&btot[tid], hist[tid]);
}

__global__ void kb_bscan(const int* __restrict__ btot, int* __restrict__ bbase, int* __restrict__ bcur){
  __shared__ int sd[256];
  int tid = threadIdx.x;
  int v = (tid < NB) ? btot[tid] : 0;
  sd[tid] = v;
  __syncthreads();
  for (int o = 1; o < 256; o <<= 1){
    int t = (tid >= o) ? sd[tid - o] : 0;
    __syncthreads();
    sd[tid] += t;
    __syncthreads();
  }
  if (tid < NB){ bbase[tid] = sd[tid] - v; bcur[tid] = sd[tid] - v; }
}

__global__ __launch_bounds__(256) void kb_scatter(const int* __restrict__ src, const int* __restrict__ dst,
                                                  int* __restrict__ bcur, u32* __restrict__ buf){
  __shared__ int hist[256];
  __shared__ int lcur[256];
  int tid = threadIdx.x;
  hist[tid] = 0;
  __syncthreads();
  int e0 = blockIdx.x * EPB, e1 = min(e0 + EPB, EE);
  for (int e = e0 + tid; e < e1; e += 256) atomicAdd(&hist[dst[e] >> 8], 1);
  __syncthreads();
  if (tid < NB && hist[tid]) lcur[tid] = atomicAdd(&bcur[tid], hist[tid]);
  __syncthreads();
  for (int e = e0 + tid; e < e1; e += 256){
    int d = dst[e];
    int pos = atomicAdd(&lcur[d >> 8], 1);
    buf[pos] = (u32)src[e] | ((u32)(d & 255) << 16);
  }
}

__global__ __launch_bounds__(256) void kb_finalize(const u32* __restrict__ buf,
                                                   const int* __restrict__ btot, const int* __restrict__ bbase,
                                                   int* __restrict__ offs, int* __restrict__ cnt,
                                                   u16* __restrict__ srcs){
  __shared__ int dh[256];
  __shared__ int sd[256];
  __shared__ int dcur[256];
  int tid = threadIdx.x, b = blockIdx.x;
  int n = btot[b], base = bbase[b];
  dh[tid] = 0;
  __syncthreads();
  for (int i = tid; i < n; i += 256) atomicAdd(&dh[(buf[base + i] >> 16) & 255], 1);
  __syncthreads();
  int v = dh[tid];
  sd[tid] = v;
  __syncthreads();
  for (int o = 1; o < 256; o <<= 1){
    int t = (tid >= o) ? sd[tid - o] : 0;
    __syncthreads();
    sd[tid] += t;
    __syncthreads();
  }
  int excl = sd[tid] - v;
  dcur[tid] = base + excl;
  int d = (b << 8) + tid;
  if (d < NN){ offs[d] = base + excl; cnt[d] = v; }
  __syncthreads();
  for (int i = tid; i < n; i += 256){
    u32 u = buf[base + i];
    int pos = atomicAdd(&dcur[(u >> 16) & 255], 1);
    srcs[pos] = (u16)(u & 0xffffu);
  }
}

// one-time: rewrite W[K=128][N=nct*16] into per-lane fp16 MFMA B-fragments:
// Wf[s*8+j], s = (ks*nct+t)*64+lane : W[ks*32+(lane>>4)*8+j][t*16+(lane&15)]
__global__ void kp_wfrag(const void* __restrict__ W, u16* __restrict__ Wf,
                         const int* __restrict__ flagp, int nct){
  int isbf = *flagp;
  int s = blockIdx.x * 64 + threadIdx.x;
  if (s >= 4 * nct * 64) return;
  int lane = s & 63;
  int t  = (s >> 6) % nct;
  int ks = (s >> 6) / nct;
  int q = lane >> 4, n = lane & 15;
  int N = nct * 16;
  u16 tmp[8];
  #pragma unroll
  for (int j = 0; j < 8; ++j)
    tmp[j] = f2h(ldv(W, (ks * 32 + q * 8 + j) * N + t * 16 + n, isbf));
  *(uint4*)(Wf + (size_t)s * 8) = *(const uint4*)tmp;
}

// MFMA GEMM: H = X·W (fp16), one wave per 16-row tile, W fragments in LDS,
// A-fragments straight from global. Fused Sv/Dv epilogue (fp32).
__global__ __launch_bounds__(256) void k_gemm(const void* __restrict__ X,
                                              const u16* __restrict__ Wf,
                                              u16* __restrict__ Hout,
                                              const void* __restrict__ as,
                                              const void* __restrict__ ad,
                                              float* __restrict__ Sv, float* __restrict__ Dv,
                                              const int* __restrict__ flagp, int xext){
  __shared__ uint4 Wl[2048];   // 32 KB
  int isbf = *flagp;
  int tid = threadIdx.x;
  const uint4* Wg = (const uint4*)Wf;
  #pragma unroll
  for (int i = 0; i < 8; ++i) Wl[tid + 256 * i] = Wg[tid + 256 * i];
  __syncthreads();
  int wv = tid >> 6, lane = tid & 63;
  int rtile = blockIdx.x * 4 + wv;
  if (rtile >= NTILE) return;        // no barriers after this point
  int q = lane >> 4, n = lane & 15;
  int arow = rtile * 16 + n;
  f32x4 acc[8];
  #pragma unroll
  for (int t = 0; t < 8; ++t) acc[t] = (f32x4){0.f, 0.f, 0.f, 0.f};
  union F8 { uint4 u; f16x8 v; f16 h[8]; };
  #pragma unroll
  for (int ks = 0; ks < 4; ++ks){
    int kb = ks * 32 + q * 8;
    F8 a;
    if (!xext){
      a.u = *(const uint4*)((const u16*)X + (size_t)arow * DD + kb);   // internal fp16
    } else if (isbf){
      const u16* xp = (const u16*)X + (size_t)arow * DD + kb;
      uint4 r = *(const uint4*)xp;
      const u16* rp = (const u16*)&r;
      #pragma unroll
      for (int j = 0; j < 8; ++j) a.h[j] = (f16)bf2f((u32)rp[j]);
    } else {
      const float* xp = (const float*)X + (size_t)arow * DD + kb;
      float4 f0 = *(const float4*)xp;
      float4 f1 = *(const float4*)(xp + 4);
      a.h[0] = (f16)f0.x; a.h[1] = (f16)f0.y; a.h[2] = (f16)f0.z; a.h[3] = (f16)f0.w;
      a.h[4] = (f16)f1.x; a.h[5] = (f16)f1.y; a.h[6] = (f16)f1.z; a.h[7] = (f16)f1.w;
    }
    #pragma unroll
    for (int t = 0; t < 8; ++t){
      F8 b; b.u = Wl[(ks * 8 + t) * 64 + lane];
      acc[t] = __builtin_amdgcn_mfma_f32_16x16x32_f16(a.v, b.v, acc[t], 0, 0, 0);
    }
  }
  // epilogue: Sv/Dv partials (lane holds rows q*4+rg, col t*16+n)
  float ps[4] = {0, 0, 0, 0}, pd[4] = {0, 0, 0, 0};
  #pragma unroll
  for (int t = 0; t < 8; ++t){
    float a_s = ldv(as, t * 16 + n, isbf);
    float a_d = ldv(ad, t * 16 + n, isbf);
    #pragma unroll
    for (int rg = 0; rg < 4; ++rg){
      ps[rg] += acc[t][rg] * a_s;
      pd[rg] += acc[t][rg] * a_d;
    }
  }
  #pragma unroll
  for (int rg = 0; rg < 4; ++rg){
    #pragma unroll
    for (int s = 1; s < 16; s <<= 1){
      ps[rg] += __shfl_xor(ps[rg], s, 64);
      pd[rg] += __shfl_xor(pd[rg], s, 64);
    }
  }
  #pragma unroll
  for (int rg = 0; rg < 4; ++rg){
    int grow = rtile * 16 + q * 4 + rg;
    if (n == 0){ Sv[grow] = ps[rg]; Dv[grow] = pd[rg]; }
    #pragma unroll
    for (int t = 0; t < 8; ++t)
      Hout[(size_t)grow * DD + t * 16 + n] = f2h(acc[t][rg]);
  }
}

// one wave per destination: phase A softmax weights into LDS; phase B pure fp16
// packed-FMA gather (v_pk_fma_f16, no unpack). Epilogue fp32.
__global__ __launch_bounds__(256) void k_agg(const u16* __restrict__ H,
                                             const float* __restrict__ Sv, const float* __restrict__ Dv,
                                             const int* __restrict__ offs, const int* __restrict__ cnt,
                                             const u16* __restrict__ srcs,
                                             const void* __restrict__ bias,
                                             u16* __restrict__ Xout, int do_relu,
                                             const int* __restrict__ flagp){
  __shared__ int   s_i[4][MAXD];
  __shared__ float s_w[4][MAXD];
  int isbf = *flagp;
  int gid = blockIdx.x * blockDim.x + threadIdx.x;
  int wid = gid >> 6, lane = gid & 63;
  int wv = threadIdx.x >> 6;
  if (wid >= NN) return;
  int off = offs[wid], c = cnt[wid];
  float dvw = Dv[wid];
  float eself = fmaxf(Sv[wid] + dvw, 0.f);
  float mS = -1e30f;
  for (int j = lane; j < c; j += 64){
    int sidx = (int)srcs[off + j];
    float s = Sv[sidx];
    if (j < MAXD){ s_i[wv][j] = sidx; s_w[wv][j] = s; }
    mS = fmaxf(mS, s);
  }
  mS = wave_max(mS);
  float m = fmaxf(eself, fmaxf(mS + dvw, 0.f));
  float wself = __expf(eself - m);
  int cf = min(c, MAXD);
  float dl = 0.f;
  for (int j = lane; j < cf; j += 64){
    float wgt = __expf(fmaxf(s_w[wv][j] + dvw, 0.f) - m);
    s_w[wv][j] = wgt;
    dl += wgt;
  }
  int grp = lane >> 4, cg = lane & 15;
  const u32* H32 = (const u32*)H;
  union F8 { uint4 u; h2 p[4]; };
  h2 acc2[4] = {(h2){0,0},(h2){0,0},(h2){0,0},(h2){0,0}};
  if (grp == 0){
    F8 r; r.u = *(const uint4*)(H32 + (size_t)wid * 64 + cg * 4);
    f16 wh = (f16)wself; h2 w2 = {wh, wh};
    #pragma unroll
    for (int i = 0; i < 4; ++i) acc2[i] = r.p[i] * w2;
  }
  // phase B: packed fp16 gather
  for (int base = 0; base < cf; base += 4){
    int j = base + grp;
    float wgt = 0.f; int sidx = 0;
    if (j < cf){ wgt = s_w[wv][j]; sidx = s_i[wv][j]; }
    f16 wh = (f16)wgt; h2 w2 = {wh, wh};
    F8 r; r.u = *(const uint4*)(H32 + (size_t)sidx * 64 + cg * 4);
    #pragma unroll
    for (int i = 0; i < 4; ++i) acc2[i] += r.p[i] * w2;
  }
  for (int base = MAXD; base < c; base += 4){   // ultra-rare tail
    int j = base + grp;
    bool valid = j < c;
    int sidx = valid ? (int)srcs[off + j] : 0;
    float e = fmaxf(Sv[sidx] + dvw, 0.f);
    float wgt = valid ? __expf(e - m) : 0.f;
    if (cg == 0) dl += wgt;
    f16 wh = (f16)wgt; h2 w2 = {wh, wh};
    F8 r; r.u = *(const uint4*)(H32 + (size_t)sidx * 64 + cg * 4);
    #pragma unroll
    for (int i = 0; i < 4; ++i) acc2[i] += r.p[i] * w2;
  }
  union FU { h2 v; float f; };
  #pragma unroll
  for (int i = 0; i < 4; ++i){
    FU a; a.v = acc2[i];
    FU o1; o1.f = __shfl_xor(a.f, 16, 64); a.v = a.v + o1.v;
    FU o2; o2.f = __shfl_xor(a.f, 32, 64); a.v = a.v + o2.v;
    acc2[i] = a.v;
  }
  float denom = wave_sum(dl) + wself;
  float inv = 1.f / denom;
  if (grp == 0){
    uint4 pk;
    u32* pkp = (u32*)&pk;
    #pragma unroll
    for (int qq = 0; qq < 4; ++qq){
      float o0 = (float)acc2[qq].x * inv + ldv(bias, cg * 8 + 2 * qq,     isbf);
      float o1 = (float)acc2[qq].y * inv + ldv(bias, cg * 8 + 2 * qq + 1, isbf);
      if (do_relu){ o0 = fmaxf(o0, 0.f); o1 = fmaxf(o1, 0.f); }
      pkp[qq] = ((u32)f2h(o1) << 16) | (u32)f2h(o0);
    }
    *(uint4*)((u32*)Xout + (size_t)wid * 64 + cg * 4) = pk;
  }
}

// out = X·Wout + b via MFMA; X fp16, Wout pre-formatted fragments (nct=4).
__global__ __launch_bounds__(256) void k_out(const u16* __restrict__ X,
                                             const u16* __restrict__ Wfo,
                                             const void* __restrict__ bias,
                                             void* __restrict__ out,
                                             const int* __restrict__ flagp){
  __shared__ uint4 Wl[1024];   // 16 KB
  int isbf = *flagp;
  int tid = threadIdx.x;
  const uint4* Wg = (const uint4*)Wfo;
  #pragma unroll
  for (int i = 0; i < 4; ++i) Wl[tid + 256 * i] = Wg[tid + 256 * i];
  __syncthreads();
  int wv = tid >> 6, lane = tid & 63;
  int rtile = blockIdx.x * 4 + wv;
  if (rtile >= NTILE) return;
  int q = lane >> 4, n = lane & 15;
  int arow = rtile * 16 + n;
  f32x4 acc[4];
  #pragma unroll
  for (int t = 0; t < 4; ++t) acc[t] = (f32x4){0.f, 0.f, 0.f, 0.f};
  union F8 { uint4 u; f16x8 v; };
  #pragma unroll
  for (int ks = 0; ks < 4; ++ks){
    F8 a; a.u = *(const uint4*)(X + (size_t)arow * DD + ks * 32 + q * 8);
    #pragma unroll
    for (int t = 0; t < 4; ++t){
      F8 b; b.u = Wl[(ks * 4 + t) * 64 + lane];
      acc[t] = __builtin_amdgcn_mfma_f32_16x16x32_f16(a.v, b.v, acc[t], 0, 0, 0);
    }
  }
  float bo[4];
  #pragma unroll
  for (int t = 0; t < 4; ++t) bo[t] = ldv(bias, t * 16 + n, isbf);
  #pragma unroll
  for (int rg = 0; rg < 4; ++rg){
    int grow = rtile * 16 + q * 4 + rg;
    #pragma unroll
    for (int t = 0; t < 4; ++t){
      float v = acc[t][rg] + bo[t];
      size_t oi = (size_t)grow * DYY + t * 16 + n;
      if (isbf) ((u16*)out)[oi] = f2bf(v);
      else      ((float*)out)[oi] = v;
    }
  }
}

extern "C" void kernel_launch(void* const* d_in, const int* in_sizes, int n_in,
                              void* d_out, int out_size, void* d_ws, size_t ws_size,
                              hipStream_t stream) {
  const void* node_x = d_in[0];
  const int* ei   = (const int*)d_in[1];
  const int* srcp = ei;
  const int* dstp = ei + EE;
  const void* W1  = d_in[2];
  const void* as1 = d_in[3];
  const void* ad1 = d_in[4];
  const void* b1  = d_in[5];
  const void* W2  = d_in[6];
  const void* as2 = d_in[7];
  const void* ad2 = d_in[8];
  const void* b2  = d_in[9];
  const void* Wo  = d_in[10];
  const void* bo  = d_in[11];

  // workspace carve: ~30 MB. buf aliases Abf (dead until first k_agg write).
  char* w = (char*)d_ws;
  u16*   Hbf  = (u16*)w;   w += (size_t)NN * DD * 2;  // 12.8 MB (fp16)
  u16*   Abf  = (u16*)w;   w += (size_t)NN * DD * 2;  // 12.8 MB (fp16; aliased by buf in CSR build)
  u32*   buf  = (u32*)Abf;
  float* Sv   = (float*)w; w += (size_t)NN * 4;
  float* Dv   = (float*)w; w += (size_t)NN * 4;
  int*   cnt  = (int*)w;   w += (size_t)NN * 4;
  int*   offs = (int*)w;   w += (size_t)NN * 4;
  int*   flagp= (int*)w;   w += 16;
  int*   btot = (int*)w;   w += 1024;
  int*   bbase= (int*)w;   w += 1024;
  int*   bcur = (int*)w;   w += 1024;
  u16*   srcs = (u16*)w;   w += (size_t)EE * 2;       // 3.2 MB
  u16*   Wf1  = (u16*)w;   w += 32768;                // fp16 fragment-layout W1
  u16*   Wf2  = (u16*)w;   w += 32768;                // fp16 fragment-layout W2
  u16*   Wfo  = (u16*)w;   w += 16384;                // fp16 fragment-layout W_out

  const int TB = 256;
  const int gWav = (NN * 64) / TB;       // 12500 (one wave per node)
  const int gMM  = (NTILE + 3) / 4;      // 782 (4 row-tiles per block)

  // dtype probe + CSR build + weight fragment prep
  k_detect   <<<1,  TB, 0, stream>>>((const u32*)W1, flagp);
  k_zero     <<<1,  TB, 0, stream>>>(btot, 256);
  kp_wfrag   <<<32, 64, 0, stream>>>(W1, Wf1, flagp, 8);
  kp_wfrag   <<<32, 64, 0, stream>>>(W2, Wf2, flagp, 8);
  kp_wfrag   <<<16, 64, 0, stream>>>(Wo, Wfo, flagp, 4);
  kb_count   <<<GB, TB, 0, stream>>>(dstp, btot);
  kb_bscan   <<<1,  TB, 0, stream>>>(btot, bbase, bcur);
  kb_scatter <<<GB, TB, 0, stream>>>(srcp, dstp, bcur, buf);
  kb_finalize<<<NB, TB, 0, stream>>>(buf, btot, bbase, offs, cnt, srcs);

  // ---- layer 1 ----
  k_gemm<<<gMM,  TB, 0, stream>>>(node_x, Wf1, Hbf, as1, ad1, Sv, Dv, flagp, 1);
  k_agg <<<gWav, TB, 0, stream>>>(Hbf, Sv, Dv, offs, cnt, srcs, b1, Abf, 1, flagp);

  // ---- layer 2 ----
  k_gemm<<<gMM,  TB, 0, stream>>>(Abf, Wf2, Hbf, as2, ad2, Sv, Dv, flagp, 0);
  k_agg <<<gWav, TB, 0, stream>>>(Hbf, Sv, Dv, offs, cnt, srcs, b2, Abf, 0, flagp);

  // ---- output projection ----
  k_out <<<gMM,  TB, 0, stream>>>(Abf, Wfo, bo, d_out, flagp);
}

// Round 9
// 315.560 us; speedup vs baseline: 2.0919x; 1.0217x over previous
//
#include <hip/hip_runtime.h>
#include <hip/hip_bf16.h>
#include <hip/hip_fp16.h>

typedef unsigned short u16;
typedef unsigned int   u32;
typedef _Float16 f16;
typedef __attribute__((ext_vector_type(8))) f16 f16x8;
typedef __attribute__((ext_vector_type(2))) f16 h2;
typedef __attribute__((ext_vector_type(4))) float f32x4;

#define NN 50000
#define EE 1600000
#define DD 128
#define DYY 64
#define NB 196      // dst buckets: dst>>8
#define EPB 8192    // edges per bucketing block
#define GB 196      // ceil(EE/EPB)
#define MAXD 160    // per-wave LDS edge cache (Poisson(32) max deg << 160)
#define NTILE 3125  // 50000 / 16 row-tiles (exact)

__device__ __forceinline__ float bf2f(u32 u){ return __uint_as_float(u << 16); }
__device__ __forceinline__ u16 f2bf(float f){
  u32 u = __float_as_uint(f);
  u += 0x7FFFu + ((u >> 16) & 1u);
  return (u16)(u >> 16);
}
__device__ __forceinline__ u16 f2h(float f){
  union { f16 h; u16 u; } x; x.h = (f16)f; return x.u;
}
// adaptive scalar load: isbf ? bf16[i] : fp32[i]
__device__ __forceinline__ float ldv(const void* p, int i, int isbf){
  return isbf ? bf2f((u32)((const u16*)p)[i]) : ((const float*)p)[i];
}

__device__ __forceinline__ float wave_sum(float v){
  #pragma unroll
  for (int s = 32; s; s >>= 1) v += __shfl_xor(v, s, 64);
  return v;
}

// dtype probe on W1 (proved fp32 in round 3; kept for robustness)
__global__ void k_detect(const u32* __restrict__ w1, int* __restrict__ flagp){
  __shared__ int cnt_s;
  if (threadIdx.x == 0) cnt_s = 0;
  __syncthreads();
  int c = 0;
  for (int i = threadIdx.x; i < 2048; i += 256){
    u32 b = (w1[i] >> 7) & 0xFFu;
    if (b >= 100u && b <= 130u) c++;
  }
  atomicAdd(&cnt_s, c);
  __syncthreads();
  if (threadIdx.x == 0) *flagp = (cnt_s > 1600) ? 1 : 0;
}

// fused prep: block 0 zeroes ALL 256 btot entries (r8 bug: only 64 were zeroed ->
// poisoned counters -> wild scatter -> memory fault); blocks 1..32 W1 frags;
// 33..64 W2; 65..80 Wout.
__device__ __forceinline__ void wfrag_one(const void* W, u16* Wf, int isbf, int nct, int s){
  int lane = s & 63;
  int t  = (s >> 6) % nct;
  int ks = (s >> 6) / nct;
  int q = lane >> 4, n = lane & 15;
  int N = nct * 16;
  u16 tmp[8];
  #pragma unroll
  for (int j = 0; j < 8; ++j)
    tmp[j] = f2h(ldv(W, (ks * 32 + q * 8 + j) * N + t * 16 + n, isbf));
  *(uint4*)(Wf + (size_t)s * 8) = *(const uint4*)tmp;
}
__global__ void k_prep(const void* __restrict__ W1, const void* __restrict__ W2,
                       const void* __restrict__ Wo, u16* __restrict__ Wf1,
                       u16* __restrict__ Wf2, u16* __restrict__ Wfo,
                       int* __restrict__ btot, const int* __restrict__ flagp){
  int b = blockIdx.x;
  if (b == 0){
    for (int i = threadIdx.x; i < 256; i += 64) btot[i] = 0;
    return;
  }
  int isbf = *flagp;
  if (b <= 32)      wfrag_one(W1, Wf1, isbf, 8, (b - 1) * 64 + (threadIdx.x & 63));
  else if (b <= 64) wfrag_one(W2, Wf2, isbf, 8, (b - 33) * 64 + (threadIdx.x & 63));
  else              wfrag_one(Wo, Wfo, isbf, 4, (b - 65) * 64 + (threadIdx.x & 63));
}

// ---- CSR build: locality-aware counting sort by dst ----
__global__ __launch_bounds__(256) void kb_count(const int* __restrict__ dst, int* __restrict__ btot){
  __shared__ int hist[256];
  int tid = threadIdx.x;
  hist[tid] = 0;
  __syncthreads();
  int e0 = blockIdx.x * EPB, e1 = min(e0 + EPB, EE);
  for (int e = e0 + tid; e < e1; e += 256) atomicAdd(&hist[dst[e] >> 8], 1);
  __syncthreads();
  if (tid < NB && hist[tid]) atomicAdd(&btot[tid], hist[tid]);
}

__global__ void kb_bscan(const int* __restrict__ btot, int* __restrict__ bbase, int* __restrict__ bcur){
  __shared__ int sd[256];
  int tid = threadIdx.x;
  int v = (tid < NB) ? btot[tid] : 0;
  sd[tid] = v;
  __syncthreads();
  for (int o = 1; o < 256; o <<= 1){
    int t = (tid >= o) ? sd[tid - o] : 0;
    __syncthreads();
    sd[tid] += t;
    __syncthreads();
  }
  if (tid < NB){ bbase[tid] = sd[tid] - v; bcur[tid] = sd[tid] - v; }
}

__global__ __launch_bounds__(256) void kb_scatter(const int* __restrict__ src, const int* __restrict__ dst,
                                                  int* __restrict__ bcur, u32* __restrict__ buf){
  __shared__ int hist[256];
  __shared__ int lcur[256];
  int tid = threadIdx.x;
  hist[tid] = 0;
  __syncthreads();
  int e0 = blockIdx.x * EPB, e1 = min(e0 + EPB, EE);
  for (int e = e0 + tid; e < e1; e += 256) atomicAdd(&hist[dst[e] >> 8], 1);
  __syncthreads();
  if (tid < NB && hist[tid]) lcur[tid] = atomicAdd(&bcur[tid], hist[tid]);
  __syncthreads();
  for (int e = e0 + tid; e < e1; e += 256){
    int d = dst[e];
    int pos = atomicAdd(&lcur[d >> 8], 1);
    buf[pos] = (u32)src[e] | ((u32)(d & 255) << 16);
  }
}

__global__ __launch_bounds__(256) void kb_finalize(const u32* __restrict__ buf,
                                                   const int* __restrict__ btot, const int* __restrict__ bbase,
                                                   int* __restrict__ offs, int* __restrict__ cnt,
                                                   u16* __restrict__ srcs){
  __shared__ int dh[256];
  __shared__ int sd[256];
  __shared__ int dcur[256];
  int tid = threadIdx.x, b = blockIdx.x;
  int n = btot[b], base = bbase[b];
  dh[tid] = 0;
  __syncthreads();
  for (int i = tid; i < n; i += 256) atomicAdd(&dh[(buf[base + i] >> 16) & 255], 1);
  __syncthreads();
  int v = dh[tid];
  sd[tid] = v;
  __syncthreads();
  for (int o = 1; o < 256; o <<= 1){
    int t = (tid >= o) ? sd[tid - o] : 0;
    __syncthreads();
    sd[tid] += t;
    __syncthreads();
  }
  int excl = sd[tid] - v;
  dcur[tid] = base + excl;
  int d = (b << 8) + tid;
  if (d < NN){ offs[d] = base + excl; cnt[d] = v; }
  __syncthreads();
  for (int i = tid; i < n; i += 256){
    u32 u = buf[base + i];
    int pos = atomicAdd(&dcur[(u >> 16) & 255], 1);
    srcs[pos] = (u16)(u & 0xffffu);
  }
}

// MFMA GEMM: H = X·W (fp16), one wave per 16-row tile, W fragments in LDS,
// A-fragments straight from global. Fused Sv/Dv epilogue (fp32).
__global__ __launch_bounds__(256) void k_gemm(const void* __restrict__ X,
                                              const u16* __restrict__ Wf,
                                              u16* __restrict__ Hout,
                                              const void* __restrict__ as,
                                              const void* __restrict__ ad,
                                              float* __restrict__ Sv, float* __restrict__ Dv,
                                              const int* __restrict__ flagp, int xext){
  __shared__ uint4 Wl[2048];   // 32 KB
  int isbf = *flagp;
  int tid = threadIdx.x;
  const uint4* Wg = (const uint4*)Wf;
  #pragma unroll
  for (int i = 0; i < 8; ++i) Wl[tid + 256 * i] = Wg[tid + 256 * i];
  __syncthreads();
  int wv = tid >> 6, lane = tid & 63;
  int rtile = blockIdx.x * 4 + wv;
  if (rtile >= NTILE) return;        // no barriers after this point
  int q = lane >> 4, n = lane & 15;
  int arow = rtile * 16 + n;
  f32x4 acc[8];
  #pragma unroll
  for (int t = 0; t < 8; ++t) acc[t] = (f32x4){0.f, 0.f, 0.f, 0.f};
  union F8 { uint4 u; f16x8 v; f16 h[8]; };
  #pragma unroll
  for (int ks = 0; ks < 4; ++ks){
    int kb = ks * 32 + q * 8;
    F8 a;
    if (!xext){
      a.u = *(const uint4*)((const u16*)X + (size_t)arow * DD + kb);   // internal fp16
    } else if (isbf){
      const u16* xp = (const u16*)X + (size_t)arow * DD + kb;
      uint4 r = *(const uint4*)xp;
      const u16* rp = (const u16*)&r;
      #pragma unroll
      for (int j = 0; j < 8; ++j) a.h[j] = (f16)bf2f((u32)rp[j]);
    } else {
      const float* xp = (const float*)X + (size_t)arow * DD + kb;
      float4 f0 = *(const float4*)xp;
      float4 f1 = *(const float4*)(xp + 4);
      a.h[0] = (f16)f0.x; a.h[1] = (f16)f0.y; a.h[2] = (f16)f0.z; a.h[3] = (f16)f0.w;
      a.h[4] = (f16)f1.x; a.h[5] = (f16)f1.y; a.h[6] = (f16)f1.z; a.h[7] = (f16)f1.w;
    }
    #pragma unroll
    for (int t = 0; t < 8; ++t){
      F8 b; b.u = Wl[(ks * 8 + t) * 64 + lane];
      acc[t] = __builtin_amdgcn_mfma_f32_16x16x32_f16(a.v, b.v, acc[t], 0, 0, 0);
    }
  }
  float ps[4] = {0, 0, 0, 0}, pd[4] = {0, 0, 0, 0};
  #pragma unroll
  for (int t = 0; t < 8; ++t){
    float a_s = ldv(as, t * 16 + n, isbf);
    float a_d = ldv(ad, t * 16 + n, isbf);
    #pragma unroll
    for (int rg = 0; rg < 4; ++rg){
      ps[rg] += acc[t][rg] * a_s;
      pd[rg] += acc[t][rg] * a_d;
    }
  }
  #pragma unroll
  for (int rg = 0; rg < 4; ++rg){
    #pragma unroll
    for (int s = 1; s < 16; s <<= 1){
      ps[rg] += __shfl_xor(ps[rg], s, 64);
      pd[rg] += __shfl_xor(pd[rg], s, 64);
    }
  }
  #pragma unroll
  for (int rg = 0; rg < 4; ++rg){
    int grow = rtile * 16 + q * 4 + rg;
    if (n == 0){ Sv[grow] = ps[rg]; Dv[grow] = pd[rg]; }
    #pragma unroll
    for (int t = 0; t < 8; ++t)
      Hout[(size_t)grow * DD + t * 16 + n] = f2h(acc[t][rg]);
  }
}

// one wave per destination. Softmax WITHOUT max-subtraction (logits = relu(.) small,
// exp fits fp32); weights normalized in LDS so fp16 accumulation is bounded (sum=1).
// Gather loop: 8 iterations of (sidx,alpha) preloaded to VGPRs, then 8 independent
// dwordx4 row loads issued back-to-back -> deep MLP, no LDS/global interleave.
__global__ __launch_bounds__(256) void k_agg(const u16* __restrict__ H,
                                             const float* __restrict__ Sv, const float* __restrict__ Dv,
                                             const int* __restrict__ offs, const int* __restrict__ cnt,
                                             const u16* __restrict__ srcs,
                                             const void* __restrict__ bias,
                                             u16* __restrict__ Xout, int do_relu,
                                             const int* __restrict__ flagp){
  __shared__ int   s_i[4][MAXD];
  __shared__ float s_w[4][MAXD];
  int isbf = *flagp;
  int gid = blockIdx.x * blockDim.x + threadIdx.x;
  int wid = gid >> 6, lane = gid & 63;
  int wv = threadIdx.x >> 6;
  if (wid >= NN) return;
  int off = offs[wid], c = cnt[wid];
  float dvw = Dv[wid];
  float wself = __expf(fmaxf(Sv[wid] + dvw, 0.f));
  int cf = min(c, MAXD);
  // phase A: per-edge weights (un-normalized) into LDS + total
  float dl = 0.f;
  for (int j = lane; j < c; j += 64){
    int sidx = (int)srcs[off + j];
    float wgt = __expf(fmaxf(Sv[sidx] + dvw, 0.f));
    if (j < MAXD){ s_i[wv][j] = sidx; s_w[wv][j] = wgt; }
    dl += wgt;
  }
  float inv = 1.f / (wave_sum(dl) + wself);
  // normalize in LDS (each lane rewrites its own slots)
  for (int j = lane; j < cf; j += 64) s_w[wv][j] *= inv;
  int grp = lane >> 4, cg = lane & 15;
  const u32* H32 = (const u32*)H;
  union F8 { uint4 u; h2 p[4]; };
  h2 acc2[4] = {(h2){0,0},(h2){0,0},(h2){0,0},(h2){0,0}};
  if (grp == 0){
    F8 r; r.u = *(const uint4*)(H32 + (size_t)wid * 64 + cg * 4);
    f16 wh = (f16)(wself * inv); h2 w2 = {wh, wh};
    #pragma unroll
    for (int i = 0; i < 4; ++i) acc2[i] = r.p[i] * w2;
  }
  // phase B: chunked gather, 8-deep load pipeline
  for (int base = 0; base < cf; base += 32){
    int nit = (cf - base + 3) >> 2;
    if (nit > 8) nit = 8;
    float w[8]; int si[8];
    #pragma unroll
    for (int t = 0; t < 8; ++t){
      int j = base + t * 4 + grp;
      bool v = (t < nit) && (j < cf);
      w[t]  = v ? s_w[wv][j] : 0.f;
      si[t] = v ? s_i[wv][j] : 0;
    }
    uint4 r[8];
    #pragma unroll
    for (int t = 0; t < 8; ++t)
      if (t < nit) r[t] = *(const uint4*)(H32 + (size_t)si[t] * 64 + cg * 4);
    #pragma unroll
    for (int t = 0; t < 8; ++t)
      if (t < nit){
        f16 wh = (f16)w[t]; h2 w2 = {wh, wh};
        F8 rr; rr.u = r[t];
        #pragma unroll
        for (int i = 0; i < 4; ++i) acc2[i] += rr.p[i] * w2;
      }
  }
  // ultra-rare tail (deg > MAXD): recompute normalized weights on the fly
  for (int base = MAXD; base < c; base += 4){
    int j = base + grp;
    bool valid = j < c;
    int sidx = valid ? (int)srcs[off + j] : 0;
    float wgt = valid ? __expf(fmaxf(Sv[sidx] + dvw, 0.f)) * inv : 0.f;
    f16 wh = (f16)wgt; h2 w2 = {wh, wh};
    F8 r; r.u = *(const uint4*)(H32 + (size_t)sidx * 64 + cg * 4);
    #pragma unroll
    for (int i = 0; i < 4; ++i) acc2[i] += r.p[i] * w2;
  }
  union FU { h2 v; float f; };
  #pragma unroll
  for (int i = 0; i < 4; ++i){
    FU a; a.v = acc2[i];
    FU o1; o1.f = __shfl_xor(a.f, 16, 64); a.v = a.v + o1.v;
    FU o2; o2.f = __shfl_xor(a.f, 32, 64); a.v = a.v + o2.v;
    acc2[i] = a.v;
  }
  if (grp == 0){
    uint4 pk;
    u32* pkp = (u32*)&pk;
    #pragma unroll
    for (int qq = 0; qq < 4; ++qq){
      float o0 = (float)acc2[qq].x + ldv(bias, cg * 8 + 2 * qq,     isbf);
      float o1 = (float)acc2[qq].y + ldv(bias, cg * 8 + 2 * qq + 1, isbf);
      if (do_relu){ o0 = fmaxf(o0, 0.f); o1 = fmaxf(o1, 0.f); }
      pkp[qq] = ((u32)f2h(o1) << 16) | (u32)f2h(o0);
    }
    *(uint4*)((u32*)Xout + (size_t)wid * 64 + cg * 4) = pk;
  }
}

// out = X·Wout + b via MFMA; X fp16, Wout pre-formatted fragments (nct=4).
__global__ __launch_bounds__(256) void k_out(const u16* __restrict__ X,
                                             const u16* __restrict__ Wfo,
                                             const void* __restrict__ bias,
                                             void* __restrict__ out,
                                             const int* __restrict__ flagp){
  __shared__ uint4 Wl[1024];   // 16 KB
  int isbf = *flagp;
  int tid = threadIdx.x;
  const uint4* Wg = (const uint4*)Wfo;
  #pragma unroll
  for (int i = 0; i < 4; ++i) Wl[tid + 256 * i] = Wg[tid + 256 * i];
  __syncthreads();
  int wv = tid >> 6, lane = tid & 63;
  int rtile = blockIdx.x * 4 + wv;
  if (rtile >= NTILE) return;
  int q = lane >> 4, n = lane & 15;
  int arow = rtile * 16 + n;
  f32x4 acc[4];
  #pragma unroll
  for (int t = 0; t < 4; ++t) acc[t] = (f32x4){0.f, 0.f, 0.f, 0.f};
  union F8 { uint4 u; f16x8 v; };
  #pragma unroll
  for (int ks = 0; ks < 4; ++ks){
    F8 a; a.u = *(const uint4*)(X + (size_t)arow * DD + ks * 32 + q * 8);
    #pragma unroll
    for (int t = 0; t < 4; ++t){
      F8 b; b.u = Wl[(ks * 4 + t) * 64 + lane];
      acc[t] = __builtin_amdgcn_mfma_f32_16x16x32_f16(a.v, b.v, acc[t], 0, 0, 0);
    }
  }
  float bo[4];
  #pragma unroll
  for (int t = 0; t < 4; ++t) bo[t] = ldv(bias, t * 16 + n, isbf);
  #pragma unroll
  for (int rg = 0; rg < 4; ++rg){
    int grow = rtile * 16 + q * 4 + rg;
    #pragma unroll
    for (int t = 0; t < 4; ++t){
      float v = acc[t][rg] + bo[t];
      size_t oi = (size_t)grow * DYY + t * 16 + n;
      if (isbf) ((u16*)out)[oi] = f2bf(v);
      else      ((float*)out)[oi] = v;
    }
  }
}

extern "C" void kernel_launch(void* const* d_in, const int* in_sizes, int n_in,
                              void* d_out, int out_size, void* d_ws, size_t ws_size,
                              hipStream_t stream) {
  const void* node_x = d_in[0];
  const int* ei   = (const int*)d_in[1];
  const int* srcp = ei;
  const int* dstp = ei + EE;
  const void* W1  = d_in[2];
  const void* as1 = d_in[3];
  const void* ad1 = d_in[4];
  const void* b1  = d_in[5];
  const void* W2  = d_in[6];
  const void* as2 = d_in[7];
  const void* ad2 = d_in[8];
  const void* b2  = d_in[9];
  const void* Wo  = d_in[10];
  const void* bo  = d_in[11];

  // workspace carve: ~30 MB. buf aliases Abf (dead until first k_agg write).
  char* w = (char*)d_ws;
  u16*   Hbf  = (u16*)w;   w += (size_t)NN * DD * 2;  // 12.8 MB (fp16)
  u16*   Abf  = (u16*)w;   w += (size_t)NN * DD * 2;  // 12.8 MB (fp16; aliased by buf in CSR build)
  u32*   buf  = (u32*)Abf;
  float* Sv   = (float*)w; w += (size_t)NN * 4;
  float* Dv   = (float*)w; w += (size_t)NN * 4;
  int*   cnt  = (int*)w;   w += (size_t)NN * 4;
  int*   offs = (int*)w;   w += (size_t)NN * 4;
  int*   flagp= (int*)w;   w += 16;
  int*   btot = (int*)w;   w += 1024;
  int*   bbase= (int*)w;   w += 1024;
  int*   bcur = (int*)w;   w += 1024;
  u16*   srcs = (u16*)w;   w += (size_t)EE * 2;       // 3.2 MB
  u16*   Wf1  = (u16*)w;   w += 32768;                // fp16 fragment-layout W1
  u16*   Wf2  = (u16*)w;   w += 32768;                // fp16 fragment-layout W2
  u16*   Wfo  = (u16*)w;   w += 16384;                // fp16 fragment-layout W_out

  const int TB = 256;
  const int gWav = (NN * 64) / TB;       // 12500 (one wave per node)
  const int gMM  = (NTILE + 3) / 4;      // 782 (4 row-tiles per block)

  // dtype probe + fused prep (btot zero + all weight fragments) + CSR build
  k_detect   <<<1,  TB, 0, stream>>>((const u32*)W1, flagp);
  k_prep     <<<81, 64, 0, stream>>>(W1, W2, Wo, Wf1, Wf2, Wfo, btot, flagp);
  kb_count   <<<GB, TB, 0, stream>>>(dstp, btot);
  kb_bscan   <<<1,  TB, 0, stream>>>(btot, bbase, bcur);
  kb_scatter <<<GB, TB, 0, stream>>>(srcp, dstp, bcur, buf);
  kb_finalize<<<NB, TB, 0, stream>>>(buf, btot, bbase, offs, cnt, srcs);

  // ---- layer 1 ----
  k_gemm<<<gMM,  TB, 0, stream>>>(node_x, Wf1, Hbf, as1, ad1, Sv, Dv, flagp, 1);
  k_agg <<<gWav, TB, 0, stream>>>(Hbf, Sv, Dv, offs, cnt, srcs, b1, Abf, 1, flagp);

  // ---- layer 2 ----
  k_gemm<<<gMM,  TB, 0, stream>>>(Abf, Wf2, Hbf, as2, ad2, Sv, Dv, flagp, 0);
  k_agg <<<gWav, TB, 0, stream>>>(Hbf, Sv, Dv, offs, cnt, srcs, b2, Abf, 0, flagp);

  // ---- output projection ----
  k_out <<<gMM,  TB, 0, stream>>>(Abf, Wfo, bo, d_out, flagp);
}

// Round 10
// 297.776 us; speedup vs baseline: 2.2168x; 1.0597x over previous
//
#include <hip/hip_runtime.h>
#include <hip/hip_fp16.h>

typedef unsigned short u16;
typedef unsigned int   u32;
typedef _Float16 f16;
typedef __attribute__((ext_vector_type(8))) f16 f16x8;
typedef __attribute__((ext_vector_type(2))) f16 h2;
typedef __attribute__((ext_vector_type(4))) float f32x4;

#define NN 50000
#define EE 1600000
#define DD 128
#define DYY 64
#define NB 196      // dst buckets: dst>>8
#define EPB 8192    // edges per bucketing chunk
#define GB 196      // ceil(EE/EPB)
#define MAXD 160    // per-wave LDS edge cache
#define NTILE 3125  // 50000/16 row tiles (exact)

__device__ __forceinline__ u16 f2h(float f){
  union { f16 h; u16 u; } x; x.h = (f16)f; return x.u;
}
__device__ __forceinline__ float wave_sum(float v){
  #pragma unroll
  for (int s = 32; s; s >>= 1) v += __shfl_xor(v, s, 64);
  return v;
}

// fp32 W[K=128][N=nct*16] -> fp16 MFMA B-fragment layout:
// slot s=(ks*nct+t)*64+lane holds W[ks*32+(lane>>4)*8+j][t*16+(lane&15)], j=0..7
__device__ __forceinline__ void wfrag_one(const float* __restrict__ W, u16* __restrict__ Wf,
                                          int nct, int s){
  int lane = s & 63;
  int t  = (s >> 6) % nct;
  int ks = (s >> 6) / nct;
  int q = lane >> 4, n = lane & 15;
  int N = nct * 16;
  u16 tmp[8];
  #pragma unroll
  for (int j = 0; j < 8; ++j)
    tmp[j] = f2h(W[(ks * 32 + q * 8 + j) * N + t * 16 + n]);
  *(uint4*)(Wf + (size_t)s * 8) = *(const uint4*)tmp;
}

// launch A: blocks 0..195 per-chunk dst-bucket histograms (plain stores, no zeroing
// dependency); 196..203 W1 frags; 204..211 W2; 212..215 Wout.
__global__ __launch_bounds__(256) void kA_prep(const int* __restrict__ dst, int* __restrict__ hist2d,
                                               const float* __restrict__ W1, const float* __restrict__ W2,
                                               const float* __restrict__ Wo,
                                               u16* __restrict__ Wf1, u16* __restrict__ Wf2,
                                               u16* __restrict__ Wfo){
  int b = blockIdx.x, tid = threadIdx.x;
  if (b < GB){
    __shared__ int hist[256];
    hist[tid] = 0;
    __syncthreads();
    int e0 = b * EPB, e1 = min(e0 + EPB, EE);
    for (int e = e0 + tid; e < e1; e += 256) atomicAdd(&hist[dst[e] >> 8], 1);
    __syncthreads();
    hist2d[b * 256 + tid] = hist[tid];
  } else if (b < 204) wfrag_one(W1, Wf1, 8, (b - 196) * 256 + tid);
  else if (b < 212)   wfrag_one(W2, Wf2, 8, (b - 204) * 256 + tid);
  else                wfrag_one(Wo, Wfo, 4, (b - 212) * 256 + tid);
}

// MFMA GEMM tile: H[rtile*16 + m] = X·W (fp16 MFMA), W fragments from LDS,
// A-fragments straight from global (xf32: convert fp32->fp16). Fused Sv/Dv epilogue.
__device__ __forceinline__ void gemm_tile(const void* __restrict__ X, int xf32,
                                          const u16* __restrict__ Wf, u16* __restrict__ Hout,
                                          const float* __restrict__ as, const float* __restrict__ ad,
                                          float* __restrict__ Sv, float* __restrict__ Dv,
                                          int blk, int tid, uint4* Wl){
  const uint4* Wg = (const uint4*)Wf;
  #pragma unroll
  for (int i = 0; i < 8; ++i) Wl[tid + 256 * i] = Wg[tid + 256 * i];
  __syncthreads();
  int wv = tid >> 6, lane = tid & 63;
  int rtile = blk * 4 + wv;
  if (rtile >= NTILE) return;          // no barriers after this point
  int q = lane >> 4, n = lane & 15;
  int arow = rtile * 16 + n;
  f32x4 acc[8];
  #pragma unroll
  for (int t = 0; t < 8; ++t) acc[t] = (f32x4){0.f, 0.f, 0.f, 0.f};
  union F8 { uint4 u; f16x8 v; f16 h[8]; };
  #pragma unroll
  for (int ks = 0; ks < 4; ++ks){
    int kb = ks * 32 + q * 8;
    F8 a;
    if (!xf32){
      a.u = *(const uint4*)((const u16*)X + (size_t)arow * DD + kb);
    } else {
      const float* xp = (const float*)X + (size_t)arow * DD + kb;
      float4 f0 = *(const float4*)xp;
      float4 f1 = *(const float4*)(xp + 4);
      a.h[0] = (f16)f0.x; a.h[1] = (f16)f0.y; a.h[2] = (f16)f0.z; a.h[3] = (f16)f0.w;
      a.h[4] = (f16)f1.x; a.h[5] = (f16)f1.y; a.h[6] = (f16)f1.z; a.h[7] = (f16)f1.w;
    }
    #pragma unroll
    for (int t = 0; t < 8; ++t){
      F8 b; b.u = Wl[(ks * 8 + t) * 64 + lane];
      acc[t] = __builtin_amdgcn_mfma_f32_16x16x32_f16(a.v, b.v, acc[t], 0, 0, 0);
    }
  }
  float ps[4] = {0, 0, 0, 0}, pd[4] = {0, 0, 0, 0};
  #pragma unroll
  for (int t = 0; t < 8; ++t){
    float a_s = as[t * 16 + n];
    float a_d = ad[t * 16 + n];
    #pragma unroll
    for (int rg = 0; rg < 4; ++rg){
      ps[rg] += acc[t][rg] * a_s;
      pd[rg] += acc[t][rg] * a_d;
    }
  }
  #pragma unroll
  for (int rg = 0; rg < 4; ++rg){
    #pragma unroll
    for (int s = 1; s < 16; s <<= 1){
      ps[rg] += __shfl_xor(ps[rg], s, 64);
      pd[rg] += __shfl_xor(pd[rg], s, 64);
    }
  }
  #pragma unroll
  for (int rg = 0; rg < 4; ++rg){
    int grow = rtile * 16 + q * 4 + rg;
    if (n == 0){ Sv[grow] = ps[rg]; Dv[grow] = pd[rg]; }
    #pragma unroll
    for (int t = 0; t < 8; ++t)
      Hout[(size_t)grow * DD + t * 16 + n] = f2h(acc[t][rg]);
  }
}

// launch B: block 0 = bucket totals + exclusive scan + per-chunk column bases;
// blocks 1..782 = layer-1 GEMM (fp32 X input).
__global__ __launch_bounds__(256) void kB_scan_gemm1(const int* __restrict__ hist2d,
                                                     int* __restrict__ chunkbase,
                                                     int* __restrict__ btot, int* __restrict__ bbase,
                                                     const float* __restrict__ X, const u16* __restrict__ Wf,
                                                     u16* __restrict__ Hout,
                                                     const float* __restrict__ as, const float* __restrict__ ad,
                                                     float* __restrict__ Sv, float* __restrict__ Dv){
  __shared__ uint4 Wl[2048];
  __shared__ int sd[256];
  int tid = threadIdx.x;
  if (blockIdx.x == 0){
    int run = 0;
    if (tid < NB){
      #pragma unroll 4
      for (int c = 0; c < GB; ++c){
        int v = hist2d[c * 256 + tid];
        chunkbase[c * 256 + tid] = run;
        run += v;
      }
    }
    sd[tid] = run;
    __syncthreads();
    for (int o = 1; o < 256; o <<= 1){
      int t = (tid >= o) ? sd[tid - o] : 0;
      __syncthreads();
      sd[tid] += t;
      __syncthreads();
    }
    if (tid < NB){ btot[tid] = run; bbase[tid] = sd[tid] - run; }
    return;
  }
  gemm_tile(X, 1, Wf, Hout, as, ad, Sv, Dv, blockIdx.x - 1, tid, Wl);
}

// launch C: scatter (src | dlow<<16) into bucket-contiguous buf, no global atomics
// (per-chunk bucket bases precomputed by kB; LDS cursors for intra-chunk order).
__global__ __launch_bounds__(256) void kC_scatter(const int* __restrict__ src, const int* __restrict__ dst,
                                                  const int* __restrict__ chunkbase,
                                                  const int* __restrict__ bbase, u32* __restrict__ buf){
  __shared__ int lcur[256];
  int tid = threadIdx.x, b = blockIdx.x;
  lcur[tid] = (tid < NB) ? (chunkbase[b * 256 + tid] + bbase[tid]) : 0;
  __syncthreads();
  int e0 = b * EPB, e1 = min(e0 + EPB, EE);
  for (int e = e0 + tid; e < e1; e += 256){
    int d = dst[e];
    int pos = atomicAdd(&lcur[d >> 8], 1);
    buf[pos] = (u32)src[e] | ((u32)(d & 255) << 16);
  }
}

// launch D: per-bucket finalize -> offs/cnt/srcs (bucket region is L2-resident)
__global__ __launch_bounds__(256) void kD_finalize(const u32* __restrict__ buf,
                                                   const int* __restrict__ btot, const int* __restrict__ bbase,
                                                   int* __restrict__ offs, int* __restrict__ cnt,
                                                   u16* __restrict__ srcs){
  __shared__ int dh[256];
  __shared__ int sd[256];
  __shared__ int dcur[256];
  int tid = threadIdx.x, b = blockIdx.x;
  int n = btot[b], base = bbase[b];
  dh[tid] = 0;
  __syncthreads();
  for (int i = tid; i < n; i += 256) atomicAdd(&dh[(buf[base + i] >> 16) & 255], 1);
  __syncthreads();
  int v = dh[tid];
  sd[tid] = v;
  __syncthreads();
  for (int o = 1; o < 256; o <<= 1){
    int t = (tid >= o) ? sd[tid - o] : 0;
    __syncthreads();
    sd[tid] += t;
    __syncthreads();
  }
  int excl = sd[tid] - v;
  dcur[tid] = base + excl;
  int d = (b << 8) + tid;
  if (d < NN){ offs[d] = base + excl; cnt[d] = v; }
  __syncthreads();
  for (int i = tid; i < n; i += 256){
    u32 u = buf[base + i];
    int pos = atomicAdd(&dcur[(u >> 16) & 255], 1);
    srcs[pos] = (u16)(u & 0xffffu);
  }
}

// one wave per destination. No-max softmax (logits = relu(.) small, exp fp32-safe);
// weights normalized in LDS (sum=1) so fp16 accumulation is bounded. Phase B is the
// round-7 simple 4-edge loop (best measured: 16 VGPR, 70% occupancy).
__global__ __launch_bounds__(256) void k_agg(const u16* __restrict__ H,
                                             const float* __restrict__ Sv, const float* __restrict__ Dv,
                                             const int* __restrict__ offs, const int* __restrict__ cnt,
                                             const u16* __restrict__ srcs,
                                             const float* __restrict__ bias,
                                             u16* __restrict__ Xout, int do_relu){
  __shared__ int   s_i[4][MAXD];
  __shared__ float s_w[4][MAXD];
  int gid = blockIdx.x * blockDim.x + threadIdx.x;
  int wid = gid >> 6, lane = gid & 63;
  int wv = threadIdx.x >> 6;
  if (wid >= NN) return;
  int off = offs[wid], c = cnt[wid];
  float dvw = Dv[wid];
  float wself = __expf(fmaxf(Sv[wid] + dvw, 0.f));
  int cf = min(c, MAXD);
  // phase A: un-normalized weights into LDS + total
  float dl = 0.f;
  for (int j = lane; j < c; j += 64){
    int sidx = (int)srcs[off + j];
    float wgt = __expf(fmaxf(Sv[sidx] + dvw, 0.f));
    if (j < MAXD){ s_i[wv][j] = sidx; s_w[wv][j] = wgt; }
    dl += wgt;
  }
  float inv = 1.f / (wave_sum(dl) + wself);
  for (int j = lane; j < cf; j += 64) s_w[wv][j] *= inv;
  int grp = lane >> 4, cg = lane & 15;
  const u32* H32 = (const u32*)H;
  union F8 { uint4 u; h2 p[4]; };
  h2 acc2[4] = {(h2){0,0},(h2){0,0},(h2){0,0},(h2){0,0}};
  if (grp == 0){
    F8 r; r.u = *(const uint4*)(H32 + (size_t)wid * 64 + cg * 4);
    f16 wh = (f16)(wself * inv); h2 w2 = {wh, wh};
    #pragma unroll
    for (int i = 0; i < 4; ++i) acc2[i] = r.p[i] * w2;
  }
  // phase B: 4 groups x 16 lanes, one row per group per iter, packed fp16 FMA
  for (int base = 0; base < cf; base += 4){
    int j = base + grp;
    float wgt = 0.f; int sidx = 0;
    if (j < cf){ wgt = s_w[wv][j]; sidx = s_i[wv][j]; }
    f16 wh = (f16)wgt; h2 w2 = {wh, wh};
    F8 r; r.u = *(const uint4*)(H32 + (size_t)sidx * 64 + cg * 4);
    #pragma unroll
    for (int i = 0; i < 4; ++i) acc2[i] += r.p[i] * w2;
  }
  // ultra-rare tail (deg > MAXD): recompute normalized weights on the fly
  for (int base = MAXD; base < c; base += 4){
    int j = base + grp;
    bool valid = j < c;
    int sidx = valid ? (int)srcs[off + j] : 0;
    float wgt = valid ? __expf(fmaxf(Sv[sidx] + dvw, 0.f)) * inv : 0.f;
    f16 wh = (f16)wgt; h2 w2 = {wh, wh};
    F8 r; r.u = *(const uint4*)(H32 + (size_t)sidx * 64 + cg * 4);
    #pragma unroll
    for (int i = 0; i < 4; ++i) acc2[i] += r.p[i] * w2;
  }
  union FU { h2 v; float f; };
  #pragma unroll
  for (int i = 0; i < 4; ++i){
    FU a; a.v = acc2[i];
    FU o1; o1.f = __shfl_xor(a.f, 16, 64); a.v = a.v + o1.v;
    FU o2; o2.f = __shfl_xor(a.f, 32, 64); a.v = a.v + o2.v;
    acc2[i] = a.v;
  }
  if (grp == 0){
    uint4 pk;
    u32* pkp = (u32*)&pk;
    #pragma unroll
    for (int qq = 0; qq < 4; ++qq){
      float o0 = (float)acc2[qq].x + bias[cg * 8 + 2 * qq];
      float o1 = (float)acc2[qq].y + bias[cg * 8 + 2 * qq + 1];
      if (do_relu){ o0 = fmaxf(o0, 0.f); o1 = fmaxf(o1, 0.f); }
      pkp[qq] = ((u32)f2h(o1) << 16) | (u32)f2h(o0);
    }
    *(uint4*)((u32*)Xout + (size_t)wid * 64 + cg * 4) = pk;
  }
}

// layer-2 GEMM (fp16 X)
__global__ __launch_bounds__(256) void k_gemm2(const u16* __restrict__ X, const u16* __restrict__ Wf,
                                               u16* __restrict__ Hout,
                                               const float* __restrict__ as, const float* __restrict__ ad,
                                               float* __restrict__ Sv, float* __restrict__ Dv){
  __shared__ uint4 Wl[2048];
  gemm_tile(X, 0, Wf, Hout, as, ad, Sv, Dv, blockIdx.x, threadIdx.x, Wl);
}

// out = X·Wout + b via MFMA; fp32 stores
__global__ __launch_bounds__(256) void k_out(const u16* __restrict__ X,
                                             const u16* __restrict__ Wfo,
                                             const float* __restrict__ bias,
                                             float* __restrict__ out){
  __shared__ uint4 Wl[1024];
  int tid = threadIdx.x;
  const uint4* Wg = (const uint4*)Wfo;
  #pragma unroll
  for (int i = 0; i < 4; ++i) Wl[tid + 256 * i] = Wg[tid + 256 * i];
  __syncthreads();
  int wv = tid >> 6, lane = tid & 63;
  int rtile = blockIdx.x * 4 + wv;
  if (rtile >= NTILE) return;
  int q = lane >> 4, n = lane & 15;
  int arow = rtile * 16 + n;
  f32x4 acc[4];
  #pragma unroll
  for (int t = 0; t < 4; ++t) acc[t] = (f32x4){0.f, 0.f, 0.f, 0.f};
  union F8 { uint4 u; f16x8 v; };
  #pragma unroll
  for (int ks = 0; ks < 4; ++ks){
    F8 a; a.u = *(const uint4*)(X + (size_t)arow * DD + ks * 32 + q * 8);
    #pragma unroll
    for (int t = 0; t < 4; ++t){
      F8 b; b.u = Wl[(ks * 4 + t) * 64 + lane];
      acc[t] = __builtin_amdgcn_mfma_f32_16x16x32_f16(a.v, b.v, acc[t], 0, 0, 0);
    }
  }
  float bo[4];
  #pragma unroll
  for (int t = 0; t < 4; ++t) bo[t] = bias[t * 16 + n];
  #pragma unroll
  for (int rg = 0; rg < 4; ++rg){
    int grow = rtile * 16 + q * 4 + rg;
    #pragma unroll
    for (int t = 0; t < 4; ++t)
      out[(size_t)grow * DYY + t * 16 + n] = acc[t][rg] + bo[t];
  }
}

extern "C" void kernel_launch(void* const* d_in, const int* in_sizes, int n_in,
                              void* d_out, int out_size, void* d_ws, size_t ws_size,
                              hipStream_t stream) {
  const float* node_x = (const float*)d_in[0];
  const int* ei   = (const int*)d_in[1];
  const int* srcp = ei;
  const int* dstp = ei + EE;
  const float* W1  = (const float*)d_in[2];
  const float* as1 = (const float*)d_in[3];
  const float* ad1 = (const float*)d_in[4];
  const float* b1  = (const float*)d_in[5];
  const float* W2  = (const float*)d_in[6];
  const float* as2 = (const float*)d_in[7];
  const float* ad2 = (const float*)d_in[8];
  const float* b2  = (const float*)d_in[9];
  const float* Wo  = (const float*)d_in[10];
  const float* bo  = (const float*)d_in[11];

  // workspace carve: ~33.5 MB. buf aliases Abf (dead until first k_agg write).
  char* w = (char*)d_ws;
  u16*   Hbf   = (u16*)w;   w += (size_t)NN * DD * 2;  // 12.8 MB (fp16)
  u16*   Abf   = (u16*)w;   w += (size_t)NN * DD * 2;  // 12.8 MB (fp16; buf alias)
  u32*   buf   = (u32*)Abf;
  float* Sv    = (float*)w; w += (size_t)NN * 4;
  float* Dv    = (float*)w; w += (size_t)NN * 4;
  int*   cnt   = (int*)w;   w += (size_t)NN * 4;
  int*   offs  = (int*)w;   w += (size_t)NN * 4;
  int*   btot  = (int*)w;   w += 1024;
  int*   bbase = (int*)w;   w += 1024;
  int*   hist2d    = (int*)w; w += GB * 256 * 4;        // 200 KB
  int*   chunkbase = (int*)w; w += GB * 256 * 4;        // 200 KB
  u16*   srcs  = (u16*)w;   w += (size_t)EE * 2;       // 3.2 MB
  u16*   Wf1   = (u16*)w;   w += 32768;
  u16*   Wf2   = (u16*)w;   w += 32768;
  u16*   Wfo   = (u16*)w;   w += 16384;

  const int TB = 256;
  const int gWav = (NN * 64) / TB;       // 12500 (one wave per node)
  const int gMM  = (NTILE + 3) / 4;      // 782

  kA_prep     <<<216,     TB, 0, stream>>>(dstp, hist2d, W1, W2, Wo, Wf1, Wf2, Wfo);
  kB_scan_gemm1<<<gMM + 1, TB, 0, stream>>>(hist2d, chunkbase, btot, bbase,
                                            node_x, Wf1, Hbf, as1, ad1, Sv, Dv);
  kC_scatter  <<<GB,      TB, 0, stream>>>(srcp, dstp, chunkbase, bbase, buf);
  kD_finalize <<<NB,      TB, 0, stream>>>(buf, btot, bbase, offs, cnt, srcs);

  k_agg  <<<gWav, TB, 0, stream>>>(Hbf, Sv, Dv, offs, cnt, srcs, b1, Abf, 1);
  k_gemm2<<<gMM,  TB, 0, stream>>>(Abf, Wf2, Hbf, as2, ad2, Sv, Dv);
  k_agg  <<<gWav, TB, 0, stream>>>(Hbf, Sv, Dv, offs, cnt, srcs, b2, Abf, 0);
  k_out  <<<gMM,  TB, 0, stream>>>(Abf, Wfo, bo, (float*)d_out);
}